// Round 11
// baseline (859.899 us; speedup 1.0000x reference)
//
#include <hip/hip_runtime.h>
#include <hip/hip_bf16.h>

using bf16 = __hip_bfloat16;
typedef unsigned short ushort_t;
typedef float f32x4 __attribute__((ext_vector_type(4)));
typedef short bf16x8 __attribute__((ext_vector_type(8)));

__device__ __forceinline__ float tof(bf16 x) { return __bfloat162float(x); }
__device__ __forceinline__ float tofu(ushort_t u) { return __uint_as_float((unsigned)u << 16); }
__device__ __forceinline__ ushort_t f2bf(float x) {
  unsigned u = __float_as_uint(x);
  return (ushort_t)((u + 0x7FFF + ((u >> 16) & 1)) >> 16);  // RNE
}
__device__ __forceinline__ float sigm(float x) { return 1.f / (1.f + __expf(-x)); }
__device__ __forceinline__ float tanh_fast(float x) {
  float e2 = __expf(2.f * x);
  return 1.f - 2.f / (e2 + 1.f);
}

#define B_ 32
#define V_ 512
#define EPS_ 0.3f

// ---- workspace layout (float elements) ----
constexpr size_t OFF_C    = 1024;       // 480
constexpr size_t OFF_S    = 1504;       // 480
constexpr size_t OFF_WEFF = 1984;       // 6144 [8][3][16][16]
constexpr size_t OFF_R    = 8128;       // [32][512][20]  (dead after irprep)
constexpr size_t OFF_I    = 335808;     // [32][512][20]
constexpr size_t OFF_G    = 663488;     // [32][512][64] (dead after k_adj)
constexpr size_t OFF_BTHI = 663488;     // bf16 BT_hi [1024][512] (reuses G)
constexpr size_t OFF_BTLO = 925632;     // bf16 BT_lo [1024][512]
constexpr size_t OFF_ADJ  = 1712064;    // [512][512]
constexpr size_t OFF_ADJ2 = 1974208;    // [512][512]
constexpr size_t OFF_SKIP = 2236352;    // [32][16][512]
constexpr size_t OFF_X0   = 2498496;    // [32][13][16][512]
constexpr size_t OFF_X1   = 5906368;    // layer ping-pong; pre-loop scratch below:
constexpr size_t OFF_TBH  = 5906368;    // bf16 Bt_hi [512][544]
constexpr size_t OFF_TBL  = 6045632;
constexpr size_t OFF_TAH  = 6184896;    // bf16 A_hi [640][544]
constexpr size_t OFF_TAL  = 6358976;
constexpr size_t OFF_UHI  = 9314240;    // bf16 [6144][512]
constexpr size_t OFF_ULO  = 10887104;   // bf16 [6144][512]
constexpr size_t OFF_PADJ = 12722112;   // 4 x [512][512] partials
constexpr size_t OFF_WCT  = 13770688;   // WcT[64][512]+bsum[512] (must NOT alias R — R4/R5 bug)
constexpr size_t OFF_FLAG = 19013568;   // 8
constexpr size_t OFF_CIN  = 19013576;   // converted fp32 inputs (445952)
constexpr size_t WS_TOTAL = 19459584;

// ---------- dtype detection ----------
__global__ __launch_bounds__(256) void k_detect(const void* __restrict__ in0,
                                                float* __restrict__ flag) {
  __shared__ int cnt;
  if (threadIdx.x == 0) cnt = 0;
  __syncthreads();
  const unsigned short* u = (const unsigned short*)in0;
  int bad = 0;
  for (int i = threadIdx.x; i < 4096; i += 256) {
    int e = (u[i] >> 7) & 0xFF;
    if (e == 255 || (e != 0 && (e < 87 || e > 167))) bad++;
  }
  atomicAdd(&cnt, bad);
  __syncthreads();
  if (threadIdx.x == 0) flag[0] = (cnt > 200) ? 1.f : 0.f;
}

// ---------- all input conversion in one kernel ----------
struct P26 { const void* p[26]; };
__global__ __launch_bounds__(256) void k_convall(const void* __restrict__ in0, P26 ps,
                                                 float* __restrict__ dstin,
                                                 float* __restrict__ dstw,
                                                 const float* __restrict__ flag) {
  int tid = threadIdx.x;
  if (blockIdx.x < 384) {
    int i4 = blockIdx.x * 256 + tid;
    if (flag[0] > 0.5f) {
      ((float4*)dstin)[i4] = ((const float4*)in0)[i4];
    } else {
      ushort4 v = ((const ushort4*)in0)[i4];
      dstin[i4 * 4 + 0] = tofu(v.x);
      dstin[i4 * 4 + 1] = tofu(v.y);
      dstin[i4 * 4 + 2] = tofu(v.z);
      dstin[i4 * 4 + 3] = tofu(v.w);
    }
  } else {
    const int sz[26] = {32, 16, 4096, 128, 4096, 128, 2048, 128, 8192, 128,
                        128, 128, 128, 128, 256, 16, 192, 12, 480, 20,
                        10240, 512, 10240, 512, 10240, 512};
    int gid = (blockIdx.x - 384) * 256 + tid;
    if (gid >= 52736) return;
    int s = 0, off = 0;
    while (gid >= off + sz[s]) { off += sz[s]; ++s; }
    int local = gid - off;
    float v = (flag[0] > 0.5f) ? ((const float*)ps.p[s])[local]
                               : tofu(((const ushort_t*)ps.p[s])[local]);
    dstw[gid] = v;
  }
}

// ---------- precompute: folded-FFT mats, eff gconv weights, WcT+bsum, irfft B-mat ----------
__global__ __launch_bounds__(256) void k_pre(const float* __restrict__ linW,
                                             const float* __restrict__ gconvW,
                                             const float* f1W, const float* f1b,
                                             const float* f2W, const float* f2b,
                                             const float* f3W, const float* f3b,
                                             float* __restrict__ ws) {
  int idx = blockIdx.x * 256 + threadIdx.x;
  const float TWO_PI = 6.2831853071795864769f;
  if (idx < 512) {
  } else if (idx < 992) {
    int e = idx - 512, d = e / 24, n = e % 24;
    float c = 0.f, s = 0.f;
    for (int k = 0; k < 24; ++k) {
      int j = (k * n) % 24;
      float ang = TWO_PI * (float)j / 24.f;
      float w = linW[d * 24 + k];
      c += w * cosf(ang);
      s -= w * sinf(ang);
    }
    ws[OFF_C + e] = c;
    ws[OFF_S + e] = s;
  } else if (idx < 3040) {
    int e = idx - 992, i = e >> 8, co = (e >> 4) & 15, ci = e & 15;
    size_t base = (size_t)(i * 16 + co) * 64 + ci;
    float W0 = gconvW[base];
    float W1 = gconvW[base + 16];
    float W2 = gconvW[base + 32];
    float W3 = gconvW[base + 48];
    size_t o = OFF_WEFF + (size_t)i * 768 + co * 16 + ci;
    ws[o]       = EPS_ * (W0 + W2) + EPS_ * EPS_ * (W1 + W3);
    ws[o + 256] = (W0 - W2) + 2.f * EPS_ * (W1 - W3);
    ws[o + 512] = W1 + W3;
  } else if (idx < 36320) {
    int e = idx - 3040;
    if (e < 32768) {
      int k = e >> 9, w = e & 511;
      float v = 0.f;
      if (k < 20) v = f1W[w * 20 + k];
      else if (k < 40) v = f2W[w * 20 + k - 20];
      else if (k < 60) v = f3W[w * 20 + k - 40];
      ws[OFF_WCT + e] = v;
    } else {
      int w = e - 32768;
      ws[OFF_WCT + e] = f1b[w] + f2b[w] + f3b[w];
    }
  } else if (idx < 36320 + 278528) {
    int e = idx - 36320;
    int m = e / 544, kk = e - m * 544;
    float val = 0.f;
    if (kk < 514) {
      int k = kk >> 1;
      int j = (k * m) & 511;
      float ang = TWO_PI * (float)j * (1.f / 512.f);
      val = ((kk & 1) ? sinf(ang) : cosf(ang)) * (1.f / 512.f);
    }
    ushort_t h = f2bf(val);
    float hf = tofu(h);
    ((ushort_t*)(ws + OFF_TBH))[e] = h;
    ((ushort_t*)(ws + OFF_TBL))[e] = f2bf(val - hf);
  }
}

// ---------- FFT(24) folded into lin_W ----------
__global__ __launch_bounds__(256) void k_fft(const float* __restrict__ in,
                                             const float* __restrict__ linb,
                                             const float* __restrict__ ws,
                                             float* __restrict__ Rw, float* __restrict__ Iw,
                                             float* __restrict__ G) {
  __shared__ float Cl[480], Sl[480], lb[20];
  int tid = threadIdx.x;
  for (int e = tid; e < 480; e += 256) { Cl[e] = ws[OFF_C + e]; Sl[e] = ws[OFF_S + e]; }
  if (tid < 20) lb[tid] = linb[tid];
  __syncthreads();
  int gid = blockIdx.x * 256 + tid;
  int b = gid >> 9, v = gid & 511;
  float xr[24];
#pragma unroll
  for (int t = 0; t < 12; ++t) {
    size_t ib = (((size_t)t * 32 + b) * 512 + v) * 2;
    xr[2 * t] = in[ib];
    xr[2 * t + 1] = in[ib + 1];
  }
  size_t gbv = (size_t)b * 512 + v;
  for (int d = 0; d < 20; ++d) {
    float R = lb[d], I = lb[d];
#pragma unroll
    for (int n = 0; n < 24; ++n) {
      R = fmaf(xr[n], Cl[d * 24 + n], R);
      I = fmaf(xr[n], Sl[d * 24 + n], I);
    }
    Rw[gbv * 20 + d] = R;
    Iw[gbv * 20 + d] = I;
    G[gbv * 64 + 20 + d] = sqrtf(R * R + I * I);
    G[gbv * 64 + 40 + d] = atanf(R / (I + 1e-4f));
  }
  G[gbv * 64 + 60] = 0.f; G[gbv * 64 + 61] = 0.f;
  G[gbv * 64 + 62] = 0.f; G[gbv * 64 + 63] = 0.f;
}

// ---------- pack irfft A-matrix ----------
__global__ __launch_bounds__(256) void k_irprep(const float* __restrict__ Rw,
                                                const float* __restrict__ Iw,
                                                ushort_t* __restrict__ Ahi,
                                                ushort_t* __restrict__ Alo) {
  int e = blockIdx.x * 256 + threadIdx.x;
  if (e >= 348160) return;
  int row = e / 544, kk = e - row * 544;
  int b = row / 20, d = row - b * 20;
  float val = 0.f;
  if (kk < 514) {
    int k = kk >> 1;
    float ck = (k == 0 || k == 256) ? 1.f : 2.f;
    size_t src = ((size_t)b * 512 + k) * 20 + d;
    val = (kk & 1) ? (-ck * Iw[src]) : (ck * Rw[src]);
  }
  ushort_t h = f2bf(val);
  Ahi[e] = h;
  Alo[e] = f2bf(val - tofu(h));
}

// ---------- irfft as MFMA GEMM ----------
__global__ __launch_bounds__(512) void k_irgemm(const ushort_t* __restrict__ Ah_g,
                                                const ushort_t* __restrict__ Al_g,
                                                const ushort_t* __restrict__ Bh_g,
                                                const ushort_t* __restrict__ Bl_g,
                                                float* __restrict__ G) {
  __shared__ ushort_t Ah[128 * 40], Al[128 * 40], Bh[64 * 40], Bl[64 * 40];
  int tid = threadIdx.x;
  int lane = tid & 63, wv = tid >> 6;
  int quad = lane >> 4, l15 = lane & 15;
  int wr = wv >> 1, wc = wv & 1;
  int m0 = blockIdx.x * 128;
  int nv0 = blockIdx.y * 64;
  int srow = tid >> 2, seg = tid & 3;
  size_t baseA = (size_t)(m0 + srow) * 544 + seg * 8;
  size_t baseB = (size_t)(nv0 + (srow & 63)) * 544 + seg * 8;
  int slo = srow * 40 + seg * 8;
  uint4 pAh = *(const uint4*)&Ah_g[baseA];
  uint4 pAl = *(const uint4*)&Al_g[baseA];
  uint4 pBh, pBl;
  if (tid < 256) { pBh = *(const uint4*)&Bh_g[baseB]; pBl = *(const uint4*)&Bl_g[baseB]; }
  f32x4 acc[2][2] = {};
  for (int kt = 0; kt < 17; ++kt) {
    *(uint4*)&Ah[slo] = pAh;
    *(uint4*)&Al[slo] = pAl;
    if (tid < 256) { *(uint4*)&Bh[slo] = pBh; *(uint4*)&Bl[slo] = pBl; }
    __syncthreads();
    if (kt < 16) {
      int ko = (kt + 1) * 32;
      pAh = *(const uint4*)&Ah_g[baseA + ko];
      pAl = *(const uint4*)&Al_g[baseA + ko];
      if (tid < 256) { pBh = *(const uint4*)&Bh_g[baseB + ko]; pBl = *(const uint4*)&Bl_g[baseB + ko]; }
    }
    bf16x8 afh[2], afl[2], bfh[2], bfl[2];
#pragma unroll
    for (int i = 0; i < 2; ++i) {
      int mr = (wr * 32 + i * 16 + l15) * 40 + quad * 8;
      afh[i] = *(const bf16x8*)&Ah[mr];
      afl[i] = *(const bf16x8*)&Al[mr];
    }
#pragma unroll
    for (int j = 0; j < 2; ++j) {
      int nr = (wc * 32 + j * 16 + l15) * 40 + quad * 8;
      bfh[j] = *(const bf16x8*)&Bh[nr];
      bfl[j] = *(const bf16x8*)&Bl[nr];
    }
#pragma unroll
    for (int i = 0; i < 2; ++i)
#pragma unroll
      for (int j = 0; j < 2; ++j) {
        acc[i][j] = __builtin_amdgcn_mfma_f32_16x16x32_bf16(afh[i], bfh[j], acc[i][j], 0, 0, 0);
        acc[i][j] = __builtin_amdgcn_mfma_f32_16x16x32_bf16(afh[i], bfl[j], acc[i][j], 0, 0, 0);
        acc[i][j] = __builtin_amdgcn_mfma_f32_16x16x32_bf16(afl[i], bfh[j], acc[i][j], 0, 0, 0);
      }
    __syncthreads();
  }
#pragma unroll
  for (int i = 0; i < 2; ++i)
#pragma unroll
    for (int j = 0; j < 2; ++j)
#pragma unroll
      for (int r = 0; r < 4; ++r) {
        int arow = m0 + wr * 32 + i * 16 + quad * 4 + r;
        int col = nv0 + wc * 32 + j * 16 + l15;
        int b = arow / 20, d = arow - b * 20;
        G[((size_t)b * 512 + col) * 64 + d] = acc[i][j][r];
      }
}

// ---------- adj partials: no atomics; grid (8,8,4), 8 batches/block ----------
__global__ __launch_bounds__(256) void k_adj(const float* __restrict__ G,
                                             const float* __restrict__ wct,
                                             float* __restrict__ padj) {
  __shared__ float As[64 * 68], Bs[64 * 68], bsl[64];
  int tid = threadIdx.x, tx = tid & 15, ty = tid >> 4;
  int w0 = blockIdx.x * 64, m0 = blockIdx.y * 64, z = blockIdx.z;
  for (int i = 0; i < 16; ++i) {
    int idx = tid + i * 256;
    Bs[(idx >> 6) * 68 + (idx & 63)] = wct[(size_t)(idx >> 6) * 512 + w0 + (idx & 63)];
  }
  if (tid < 64) bsl[tid] = wct[32768 + w0 + tid];
  float sum[4][4] = {};
  for (int bi = 0; bi < 8; ++bi) {
    int bb = z * 8 + bi;
    __syncthreads();
    for (int i = 0; i < 4; ++i) {
      int idx = tid + i * 256;
      int row = idx >> 4, seg = idx & 15;
      float4 g = *(const float4*)&G[((size_t)bb * 512 + m0 + row) * 64 + seg * 4];
      As[(seg * 4 + 0) * 68 + row] = g.x;
      As[(seg * 4 + 1) * 68 + row] = g.y;
      As[(seg * 4 + 2) * 68 + row] = g.z;
      As[(seg * 4 + 3) * 68 + row] = g.w;
    }
    __syncthreads();
    float dot[4][4] = {};
    for (int kk = 0; kk < 64; ++kk) {
      float4 a = *(const float4*)&As[kk * 68 + ty * 4];
      float4 b = *(const float4*)&Bs[kk * 68 + tx * 4];
      float ar[4] = {a.x, a.y, a.z, a.w}, br[4] = {b.x, b.y, b.z, b.w};
#pragma unroll
      for (int r = 0; r < 4; ++r)
#pragma unroll
        for (int c = 0; c < 4; ++c) dot[r][c] = fmaf(ar[r], br[c], dot[r][c]);
    }
#pragma unroll
    for (int r = 0; r < 4; ++r)
#pragma unroll
      for (int c = 0; c < 4; ++c)
        sum[r][c] += sigm((dot[r][c] + bsl[tx * 4 + c]) * (1.f / 3.f));
  }
  float* pz = padj + (size_t)z * 262144;
#pragma unroll
  for (int r = 0; r < 4; ++r)
#pragma unroll
    for (int c = 0; c < 4; ++c)
      pz[(size_t)(m0 + ty * 4 + r) * 512 + w0 + tx * 4 + c] = sum[r][c];
}

// ---------- finalize adj ----------
__global__ __launch_bounds__(256) void k_adjfin(const float* __restrict__ padj,
                                                float* __restrict__ adjw,
                                                void* __restrict__ outp,
                                                const float* __restrict__ flag) {
  int idx = blockIdx.x * 256 + threadIdx.x;
  float s = padj[idx] + padj[idx + 262144] + padj[idx + 524288] + padj[idx + 786432];
  float a = sigm(s * (1.f / 32.f));
  adjw[idx] = a;
  if (flag[0] > 0.5f) ((float*)outp)[196608 + idx] = a;
  else ((ushort_t*)outp)[196608 + idx] = f2bf(a);
}

// ---------- fp32 GEMM (adj2 = adj @ adj) ----------
__global__ __launch_bounds__(256) void k_gemm(const float* __restrict__ A,
                                              const float* __restrict__ B0,
                                              const float* __restrict__ B1,
                                              float* __restrict__ C, int ldc) {
  __shared__ float As[32][68];
  __shared__ float Bs[32][68];
  int bx = blockIdx.x, by = blockIdx.y;
  const float* __restrict__ Bp = (bx < 8) ? B0 : B1;
  int n0 = (bx & 7) * 64, m0 = by * 64;
  int tid = threadIdx.x, tx = tid & 15, ty = tid >> 4;
  float acc[4][4] = {};
  for (int kb = 0; kb < 512; kb += 32) {
#pragma unroll
    for (int s = 0; s < 2; ++s) {
      int f = tid + s * 256;
      int row = f >> 3, k4 = (f & 7) << 2;
      float4 a4 = *(const float4*)(A + (size_t)(m0 + row) * 512 + kb + k4);
      As[k4 + 0][row] = a4.x;
      As[k4 + 1][row] = a4.y;
      As[k4 + 2][row] = a4.z;
      As[k4 + 3][row] = a4.w;
      int kk = f >> 4, c4 = (f & 15) << 2;
      *(float4*)&Bs[kk][c4] = *(const float4*)(Bp + (size_t)(kb + kk) * 512 + n0 + c4);
    }
    __syncthreads();
#pragma unroll
    for (int kk = 0; kk < 32; ++kk) {
      float4 a = *(const float4*)&As[kk][ty << 2];
      float4 b = *(const float4*)&Bs[kk][tx << 2];
      float ar[4] = {a.x, a.y, a.z, a.w}, br[4] = {b.x, b.y, b.z, b.w};
#pragma unroll
      for (int r = 0; r < 4; ++r)
#pragma unroll
        for (int c = 0; c < 4; ++c) acc[r][c] = fmaf(ar[r], br[c], acc[r][c]);
    }
    __syncthreads();
  }
#pragma unroll
  for (int r = 0; r < 4; ++r) {
    float4 o = make_float4(acc[r][0], acc[r][1], acc[r][2], acc[r][3]);
    *(float4*)(C + (size_t)(m0 + (ty << 2) + r) * ldc + bx * 64 + (tx << 2)) = o;
  }
}

// ---------- split B = [adjT | adj2T] into bf16 hi/lo ----------
__global__ __launch_bounds__(256) void k_splitB(const float* __restrict__ adjw,
                                                const float* __restrict__ adj2w,
                                                ushort_t* __restrict__ Bh,
                                                ushort_t* __restrict__ Bl) {
  __shared__ float til[32][33];
  int tid = threadIdx.x;
  int k0 = blockIdx.x * 32;
  int nb = blockIdx.y;
  const float* src = (nb < 16) ? adjw : adj2w;
  int ns = (nb * 32) & 511;
  for (int i = 0; i < 4; ++i) {
    int idx = tid + i * 256;
    int r = idx >> 5, c = idx & 31;
    til[r][c] = src[(size_t)(k0 + r) * 512 + ns + c];
  }
  __syncthreads();
  for (int i = 0; i < 4; ++i) {
    int idx = tid + i * 256;
    int rr = idx >> 5, cc = idx & 31;
    float v = til[cc][rr];
    ushort_t h = f2bf(v);
    float hf = tofu(h);
    ushort_t l = f2bf(v - hf);
    size_t o = (size_t)(nb * 32 + rr) * 512 + k0 + cc;
    Bh[o] = h;
    Bl[o] = l;
  }
}

// ---------- start conv ----------
__global__ __launch_bounds__(256) void k_start(const float* __restrict__ in,
                                               const float* __restrict__ stW,
                                               const float* __restrict__ stb,
                                               float* __restrict__ X0) {
  __shared__ float w[32], bl[16];
  int tid = threadIdx.x;
  if (tid < 32) w[tid] = stW[tid];
  if (tid < 16) bl[tid] = stb[tid];
  __syncthreads();
  int blk = blockIdx.x;
  int b = blk / 26, rem = blk % 26, t = rem >> 1, v = (rem & 1) * 256 + tid;
  float f0 = 0.f, f1 = 0.f;
  if (t > 0) {
    size_t ib = (((size_t)(t - 1) * 32 + b) * 512 + v) * 2;
    f0 = in[ib];
    f1 = in[ib + 1];
  }
#pragma unroll
  for (int c = 0; c < 16; ++c)
    X0[((size_t)(b * 13 + t) * 16 + c) * 512 + v] = fmaf(w[c * 2], f0, fmaf(w[c * 2 + 1], f1, bl[c]));
}

// ---------- gated conv + skip + bf16 hi/lo split of U ----------
__global__ __launch_bounds__(256) void k_gate(const float* __restrict__ X,
                                              ushort_t* __restrict__ Uhi,
                                              ushort_t* __restrict__ Ulo,
                                              float* __restrict__ skip,
                                              const float* fW, const float* fb,
                                              const float* gW, const float* gb,
                                              const float* sW, const float* sb,
                                              int i, int L, int Lo, int d) {
  __shared__ float wf[512], wg[512], swl[256], fbl[16], gbl[16], sbl[16];
  int tid = threadIdx.x;
  for (int e = tid; e < 512; e += 256) { wf[e] = fW[i * 512 + e]; wg[e] = gW[i * 512 + e]; }
  if (tid < 256) swl[tid] = sW[i * 256 + tid];
  if (tid < 16) { fbl[tid] = fb[i * 16 + tid]; gbl[tid] = gb[i * 16 + tid]; sbl[tid] = sb[i * 16 + tid]; }
  __syncthreads();
  int blk = blockIdx.x;
  int b = blk / (2 * Lo), rem = blk % (2 * Lo), t = rem >> 1, v = (rem & 1) * 256 + tid;
  float x0[16], x1[16];
  size_t base0 = (size_t)(b * L + t) * 16 * 512 + v;
  size_t base1 = (size_t)(b * L + t + d) * 16 * 512 + v;
#pragma unroll
  for (int ci = 0; ci < 16; ++ci) { x0[ci] = X[base0 + ci * 512]; x1[ci] = X[base1 + ci * 512]; }
  float u[16];
#pragma unroll
  for (int co = 0; co < 16; ++co) {
    float f = fbl[co], g = gbl[co];
#pragma unroll
    for (int ci = 0; ci < 16; ++ci) {
      f = fmaf(wf[co * 32 + ci * 2], x0[ci], f);
      f = fmaf(wf[co * 32 + ci * 2 + 1], x1[ci], f);
      g = fmaf(wg[co * 32 + ci * 2], x0[ci], g);
      g = fmaf(wg[co * 32 + ci * 2 + 1], x1[ci], g);
    }
    float uu = tanh_fast(f) * sigm(g);
    u[co] = uu;
    ushort_t h = f2bf(uu);
    float hf = tofu(h);
    ushort_t l = f2bf(uu - hf);
    size_t o = ((size_t)(b * Lo + t) * 16 + co) * 512 + v;
    Uhi[o] = h;
    Ulo[o] = l;
  }
  if (t == Lo - 1) {
#pragma unroll
    for (int c = 0; c < 16; ++c) {
      float s = sbl[c];
#pragma unroll
      for (int ci = 0; ci < 16; ++ci) s = fmaf(swl[c * 16 + ci], u[ci], s);
      skip[((size_t)b * 16 + c) * 512 + v] += s;
    }
  }
}

// ---------- fused MFMA GEMM + combine + BN: LDS staging + prefetch, 256 thr, 128x32 tile ----------
// Grid (4*Lo, 16) = 768 blocks at Lo=12 -> exactly 3 blocks/CU (balanced; inter-block overlap
// hides the per-block barrier drain). Staging converts coalesced global loads -> strided LDS
// (R10 lesson: direct-global MFMA frags are uncoalesced, 16x transaction blowup).
__global__ __launch_bounds__(256) void k_mfmac(const ushort_t* __restrict__ Uhi,
                                               const ushort_t* __restrict__ Ulo,
                                               const ushort_t* __restrict__ Bh_g,
                                               const ushort_t* __restrict__ Bl_g,
                                               const float* __restrict__ Xres,
                                               float* __restrict__ Xn,
                                               const float* __restrict__ ws,
                                               const float* gcb, const float* bg,
                                               const float* bb2, const float* bm,
                                               const float* bv,
                                               int li, int L, int Lo, int d) {
  __shared__ __align__(16) char smem[33792];   // staging 30720 B, reused as yt 33792 B
  ushort_t* Ah = (ushort_t*)smem;              // [128][40]
  ushort_t* Al = Ah + 5120;
  ushort_t* Bh = Al + 5120;                    // [64][40]
  ushort_t* Bl = Bh + 2560;
  float* yt = (float*)smem;                    // [128][66]
  __shared__ float wx[256], wy1[256], wy2[256], gbl[16], bsc[16], bsh[16];
  int tid = threadIdx.x;
  const float* we = ws + OFF_WEFF + (size_t)li * 768;
  wx[tid] = we[tid]; wy1[tid] = we[256 + tid]; wy2[tid] = we[512 + tid];
  if (tid < 16) {
    gbl[tid] = gcb[li * 16 + tid];
    float sc = bg[li * 16 + tid] * rsqrtf(bv[li * 16 + tid] + 1e-5f);
    bsc[tid] = sc;
    bsh[tid] = bb2[li * 16 + tid] - bm[li * 16 + tid] * sc;
  }
  int lane = tid & 63, wr = tid >> 6;          // 4 waves; wr owns 32 A-rows
  int quad = lane >> 4, l15 = lane & 15;
  int m0 = blockIdx.x * 128;                   // A rows (fastest grid dim: XCD A-locality)
  int nv0 = blockIdx.y * 32;                   // v-range [nv0, nv0+32)
  // staging slots: r=0,1 -> A rows 0..127; r=2 -> B rows 0..63 (32 adjT + 32 adj2T)
  size_t gbase[3];
  int lofs[3];
  {
    int seg = tid & 3;
#pragma unroll
    for (int r = 0; r < 2; ++r) {
      int row = (tid + r * 256) >> 2;
      gbase[r] = (size_t)(m0 + row) * 512 + seg * 8;
      lofs[r] = row * 40 + seg * 8;
    }
    int brow_l = ((tid + 512) >> 2) - 128;     // 0..63
    int brow = (brow_l < 32) ? (nv0 + brow_l) : (480 + nv0 + brow_l);
    gbase[2] = (size_t)brow * 512 + seg * 8;
    lofs[2] = brow_l * 40 + seg * 8;
  }
  uint4 pH[3], pL[3];
  pH[0] = *(const uint4*)&Uhi[gbase[0]];
  pL[0] = *(const uint4*)&Ulo[gbase[0]];
  pH[1] = *(const uint4*)&Uhi[gbase[1]];
  pL[1] = *(const uint4*)&Ulo[gbase[1]];
  pH[2] = *(const uint4*)&Bh_g[gbase[2]];
  pL[2] = *(const uint4*)&Bl_g[gbase[2]];
  f32x4 acc[2][4] = {};
  for (int kt = 0; kt < 16; ++kt) {
    *(uint4*)&Ah[lofs[0]] = pH[0];
    *(uint4*)&Al[lofs[0]] = pL[0];
    *(uint4*)&Ah[lofs[1]] = pH[1];
    *(uint4*)&Al[lofs[1]] = pL[1];
    *(uint4*)&Bh[lofs[2]] = pH[2];
    *(uint4*)&Bl[lofs[2]] = pL[2];
    __syncthreads();
    if (kt < 15) {
      int ko = (kt + 1) * 32;
      pH[0] = *(const uint4*)&Uhi[gbase[0] + ko];
      pL[0] = *(const uint4*)&Ulo[gbase[0] + ko];
      pH[1] = *(const uint4*)&Uhi[gbase[1] + ko];
      pL[1] = *(const uint4*)&Ulo[gbase[1] + ko];
      pH[2] = *(const uint4*)&Bh_g[gbase[2] + ko];
      pL[2] = *(const uint4*)&Bl_g[gbase[2] + ko];
    }
    bf16x8 afh[2], afl[2], bfh[4], bfl[4];
#pragma unroll
    for (int i = 0; i < 2; ++i) {
      int mr = (wr * 32 + i * 16 + l15) * 40 + quad * 8;
      afh[i] = *(const bf16x8*)&Ah[mr];
      afl[i] = *(const bf16x8*)&Al[mr];
    }
#pragma unroll
    for (int j = 0; j < 4; ++j) {
      int nr = (j * 16 + l15) * 40 + quad * 8;
      bfh[j] = *(const bf16x8*)&Bh[nr];
      bfl[j] = *(const bf16x8*)&Bl[nr];
    }
#pragma unroll
    for (int i = 0; i < 2; ++i)
#pragma unroll
      for (int j = 0; j < 4; ++j) {
        acc[i][j] = __builtin_amdgcn_mfma_f32_16x16x32_bf16(afh[i], bfh[j], acc[i][j], 0, 0, 0);
        acc[i][j] = __builtin_amdgcn_mfma_f32_16x16x32_bf16(afh[i], bfl[j], acc[i][j], 0, 0, 0);
        acc[i][j] = __builtin_amdgcn_mfma_f32_16x16x32_bf16(afl[i], bfh[j], acc[i][j], 0, 0, 0);
      }
    __syncthreads();
  }
  // ---- fused epilogue (single pass: 8 groups x 32 v) ----
#pragma unroll
  for (int i = 0; i < 2; ++i)
#pragma unroll
    for (int j = 0; j < 4; ++j)
#pragma unroll
      for (int r = 0; r < 4; ++r) {
        int row = wr * 32 + i * 16 + quad * 4 + r;
        int col = (j & 1) * 16 + l15 + (j >> 1) * 32;   // 0..31 z1, 32..63 z2
        yt[row * 66 + col] = acc[i][j][r];
      }
  __syncthreads();
  int g = tid >> 5, lv = tid & 31;
  int gg = (m0 >> 4) + g;
  int b = gg / Lo, t = gg - b * Lo;
  size_t rb = (size_t)gg * 16;
  size_t resb = ((size_t)(b * L + t + d) * 16) * 512;
  int v = nv0 + lv;
  float uu[16], z1[16], z2[16];
#pragma unroll
  for (int ci = 0; ci < 16; ++ci) {
    size_t o = (rb + ci) * 512 + v;
    uu[ci] = tofu(Uhi[o]) + tofu(Ulo[o]);
    z1[ci] = yt[(g * 16 + ci) * 66 + lv];
    z2[ci] = yt[(g * 16 + ci) * 66 + 32 + lv];
  }
#pragma unroll
  for (int co = 0; co < 16; ++co) {
    float h = gbl[co];
#pragma unroll
    for (int ci = 0; ci < 16; ++ci) {
      h = fmaf(wx[co * 16 + ci], uu[ci], h);
      h = fmaf(wy1[co * 16 + ci], z1[ci], h);
      h = fmaf(wy2[co * 16 + ci], z2[ci], h);
    }
    float val = h + Xres[resb + co * 512 + v];
    val = fmaf(val, bsc[co], bsh[co]);
    Xn[(rb + co) * 512 + v] = val;
  }
}

// ---------- epilogue ----------
__global__ __launch_bounds__(256) void k_end(const float* __restrict__ skip,
                                             const float* e1W, const float* e1b,
                                             const float* e2W, const float* e2b,
                                             void* __restrict__ outp,
                                             const float* __restrict__ flag) {
  __shared__ float w1[256], b1[16], w2[192], b2[12];
  int tid = threadIdx.x;
  if (tid < 256) w1[tid] = e1W[tid];
  if (tid < 192) w2[tid] = e2W[tid];
  if (tid < 16) b1[tid] = e1b[tid];
  if (tid < 12) b2[tid] = e2b[tid];
  __syncthreads();
  float isf32 = flag[0];
  int gid = blockIdx.x * 256 + tid;
  int b = gid >> 9, v = gid & 511;
  float sk[16], e1[16];
#pragma unroll
  for (int ci = 0; ci < 16; ++ci) sk[ci] = fmaxf(skip[((size_t)b * 16 + ci) * 512 + v], 0.f);
#pragma unroll
  for (int c = 0; c < 16; ++c) {
    float a = b1[c];
#pragma unroll
    for (int ci = 0; ci < 16; ++ci) a = fmaf(w1[c * 16 + ci], sk[ci], a);
    e1[c] = fmaxf(a, 0.f);
  }
#pragma unroll
  for (int h = 0; h < 12; ++h) {
    float o = b2[h];
#pragma unroll
    for (int ci = 0; ci < 16; ++ci) o = fmaf(w2[h * 16 + ci], e1[ci], o);
    size_t oi = ((size_t)b * 12 + h) * 512 + v;
    if (isf32 > 0.5f) ((float*)outp)[oi] = o;
    else ((ushort_t*)outp)[oi] = f2bf(o);
  }
}

extern "C" void kernel_launch(void* const* d_in, const int* in_sizes, int n_in,
                              void* d_out, int out_size, void* d_ws, size_t ws_size,
                              hipStream_t stream) {
  float* ws = (float*)d_ws;
  if (ws_size < WS_TOTAL * sizeof(float)) return;

  static const int CSZ[27] = {393216, 32, 16, 4096, 128, 4096, 128, 2048, 128, 8192, 128,
                              128, 128, 128, 128, 256, 16, 192, 12, 480, 20,
                              10240, 512, 10240, 512, 10240, 512};
  float* cv[27];
  {
    size_t off = OFF_CIN;
    for (int i = 0; i < 27; ++i) { cv[i] = ws + off; off += (size_t)CSZ[i]; }
  }
  float* flag = ws + OFF_FLAG;

  k_detect<<<1, 256, 0, stream>>>(d_in[0], flag);
  P26 ps;
  for (int i = 0; i < 26; ++i) ps.p[i] = d_in[i + 1];
  k_convall<<<590, 256, 0, stream>>>(d_in[0], ps, cv[0], cv[1], flag);

  const float* IN = cv[0];
  const float* stW = cv[1];  const float* stb = cv[2];
  const float* fW = cv[3];   const float* fb = cv[4];
  const float* gW = cv[5];   const float* gb = cv[6];
  const float* sW = cv[7];   const float* sb = cv[8];
  const float* gcW = cv[9];  const float* gcb = cv[10];
  const float* bng = cv[11]; const float* bnb = cv[12];
  const float* bnm = cv[13]; const float* bnv = cv[14];
  const float* e1W = cv[15]; const float* e1b = cv[16];
  const float* e2W = cv[17]; const float* e2b = cv[18];
  const float* linW = cv[19]; const float* linb = cv[20];
  const float* f1W = cv[21]; const float* f1b = cv[22];
  const float* f2W = cv[23]; const float* f2b = cv[24];
  const float* f3W = cv[25]; const float* f3b = cv[26];

  hipMemsetAsync(ws + OFF_SKIP, 0, (size_t)B_ * 16 * V_ * sizeof(float), stream);
  k_pre<<<1230, 256, 0, stream>>>(linW, gcW, f1W, f1b, f2W, f2b, f3W, f3b, ws);
  k_fft<<<64, 256, 0, stream>>>(IN, linb, ws, ws + OFF_R, ws + OFF_I, ws + OFF_G);
  k_irprep<<<1360, 256, 0, stream>>>(ws + OFF_R, ws + OFF_I,
                                     (ushort_t*)(ws + OFF_TAH), (ushort_t*)(ws + OFF_TAL));
  k_irgemm<<<dim3(5, 8), 512, 0, stream>>>((ushort_t*)(ws + OFF_TAH), (ushort_t*)(ws + OFF_TAL),
                                           (ushort_t*)(ws + OFF_TBH), (ushort_t*)(ws + OFF_TBL),
                                           ws + OFF_G);
  k_adj<<<dim3(8, 8, 4), 256, 0, stream>>>(ws + OFF_G, ws + OFF_WCT, ws + OFF_PADJ);
  k_adjfin<<<1024, 256, 0, stream>>>(ws + OFF_PADJ, ws + OFF_ADJ, d_out, flag);
  k_gemm<<<dim3(8, 8), 256, 0, stream>>>(ws + OFF_ADJ, ws + OFF_ADJ, ws + OFF_ADJ,
                                         ws + OFF_ADJ2, 512);
  k_splitB<<<dim3(16, 32), 256, 0, stream>>>(ws + OFF_ADJ, ws + OFF_ADJ2,
                                             (ushort_t*)(ws + OFF_BTHI),
                                             (ushort_t*)(ws + OFF_BTLO));
  k_start<<<832, 256, 0, stream>>>(IN, stW, stb, ws + OFF_X0);

  float* cur = ws + OFF_X0;
  float* nxt = ws + OFF_X1;
  ushort_t* UHI = (ushort_t*)(ws + OFF_UHI);
  ushort_t* ULO = (ushort_t*)(ws + OFF_ULO);
  int L = 13;
  const int dils[8] = {1, 2, 1, 2, 1, 2, 1, 2};
  for (int i = 0; i < 8; ++i) {
    int d = dils[i], Lo = L - d;
    k_gate<<<64 * Lo, 256, 0, stream>>>(cur, UHI, ULO, ws + OFF_SKIP,
                                        fW, fb, gW, gb, sW, sb, i, L, Lo, d);
    k_mfmac<<<dim3(4 * Lo, 16), 256, 0, stream>>>(UHI, ULO,
                                                  (ushort_t*)(ws + OFF_BTHI),
                                                  (ushort_t*)(ws + OFF_BTLO),
                                                  cur, nxt, ws,
                                                  gcb, bng, bnb, bnm, bnv, i, L, Lo, d);
    float* tmp = cur; cur = nxt; nxt = tmp;
    L = Lo;
  }
  k_end<<<64, 256, 0, stream>>>(ws + OFF_SKIP, e1W, e1b, e2W, e2b, d_out, flag);
}

// Round 12
// 543.441 us; speedup vs baseline: 1.5823x; 1.5823x over previous
//
#include <hip/hip_runtime.h>
#include <hip/hip_bf16.h>

using bf16 = __hip_bfloat16;
typedef unsigned short ushort_t;
typedef float f32x4 __attribute__((ext_vector_type(4)));
typedef short bf16x8 __attribute__((ext_vector_type(8)));

__device__ __forceinline__ float tof(bf16 x) { return __bfloat162float(x); }
__device__ __forceinline__ float tofu(ushort_t u) { return __uint_as_float((unsigned)u << 16); }
__device__ __forceinline__ ushort_t f2bf(float x) {
  unsigned u = __float_as_uint(x);
  return (ushort_t)((u + 0x7FFF + ((u >> 16) & 1)) >> 16);  // RNE
}
__device__ __forceinline__ float sigm(float x) { return 1.f / (1.f + __expf(-x)); }
__device__ __forceinline__ float tanh_fast(float x) {
  float e2 = __expf(2.f * x);
  return 1.f - 2.f / (e2 + 1.f);
}

#define B_ 32
#define V_ 512
#define EPS_ 0.3f

// ---- workspace layout (float elements) ----
constexpr size_t OFF_C    = 1024;       // 480
constexpr size_t OFF_S    = 1504;       // 480
constexpr size_t OFF_WEFF = 1984;       // 6144 [8][3][16][16]
constexpr size_t OFF_R    = 8128;       // [32][512][20]  (dead after irprep)
constexpr size_t OFF_I    = 335808;     // [32][512][20]
constexpr size_t OFF_G    = 663488;     // [32][512][64] (dead after k_adj)
constexpr size_t OFF_BTHI = 663488;     // bf16 BT_hi [1024][512] (reuses G)
constexpr size_t OFF_BTLO = 925632;     // bf16 BT_lo [1024][512]
constexpr size_t OFF_ADJ  = 1712064;    // [512][512]
constexpr size_t OFF_ADJ2 = 1974208;    // [512][512]
constexpr size_t OFF_SKIP = 2236352;    // [32][16][512]
constexpr size_t OFF_X0   = 2498496;    // [32][13][16][512]
constexpr size_t OFF_X1   = 5906368;    // layer ping-pong; pre-loop scratch below:
constexpr size_t OFF_TBH  = 5906368;    // bf16 Bt_hi [512][544]
constexpr size_t OFF_TBL  = 6045632;
constexpr size_t OFF_TAH  = 6184896;    // bf16 A_hi [640][544]
constexpr size_t OFF_TAL  = 6358976;
constexpr size_t OFF_UHI  = 9314240;    // bf16 [6144][512]
constexpr size_t OFF_ULO  = 10887104;   // bf16 [6144][512]
constexpr size_t OFF_PADJ = 12722112;   // 4 x [512][512] partials
constexpr size_t OFF_WCT  = 13770688;   // WcT[64][512]+bsum[512] (must NOT alias R — R4/R5 bug)
constexpr size_t OFF_FLAG = 19013568;   // 8
constexpr size_t OFF_CIN  = 19013576;   // converted fp32 inputs (445952)
constexpr size_t WS_TOTAL = 19459584;

// ---------- dtype detection ----------
__global__ __launch_bounds__(256) void k_detect(const void* __restrict__ in0,
                                                float* __restrict__ flag) {
  __shared__ int cnt;
  if (threadIdx.x == 0) cnt = 0;
  __syncthreads();
  const unsigned short* u = (const unsigned short*)in0;
  int bad = 0;
  for (int i = threadIdx.x; i < 4096; i += 256) {
    int e = (u[i] >> 7) & 0xFF;
    if (e == 255 || (e != 0 && (e < 87 || e > 167))) bad++;
  }
  atomicAdd(&cnt, bad);
  __syncthreads();
  if (threadIdx.x == 0) flag[0] = (cnt > 200) ? 1.f : 0.f;
}

// ---------- all input conversion in one kernel ----------
struct P26 { const void* p[26]; };
__global__ __launch_bounds__(256) void k_convall(const void* __restrict__ in0, P26 ps,
                                                 float* __restrict__ dstin,
                                                 float* __restrict__ dstw,
                                                 const float* __restrict__ flag) {
  int tid = threadIdx.x;
  if (blockIdx.x < 384) {
    int i4 = blockIdx.x * 256 + tid;
    if (flag[0] > 0.5f) {
      ((float4*)dstin)[i4] = ((const float4*)in0)[i4];
    } else {
      ushort4 v = ((const ushort4*)in0)[i4];
      dstin[i4 * 4 + 0] = tofu(v.x);
      dstin[i4 * 4 + 1] = tofu(v.y);
      dstin[i4 * 4 + 2] = tofu(v.z);
      dstin[i4 * 4 + 3] = tofu(v.w);
    }
  } else {
    const int sz[26] = {32, 16, 4096, 128, 4096, 128, 2048, 128, 8192, 128,
                        128, 128, 128, 128, 256, 16, 192, 12, 480, 20,
                        10240, 512, 10240, 512, 10240, 512};
    int gid = (blockIdx.x - 384) * 256 + tid;
    if (gid >= 52736) return;
    int s = 0, off = 0;
    while (gid >= off + sz[s]) { off += sz[s]; ++s; }
    int local = gid - off;
    float v = (flag[0] > 0.5f) ? ((const float*)ps.p[s])[local]
                               : tofu(((const ushort_t*)ps.p[s])[local]);
    dstw[gid] = v;
  }
}

// ---------- precompute: folded-FFT mats, eff gconv weights, WcT+bsum, irfft B-mat ----------
__global__ __launch_bounds__(256) void k_pre(const float* __restrict__ linW,
                                             const float* __restrict__ gconvW,
                                             const float* f1W, const float* f1b,
                                             const float* f2W, const float* f2b,
                                             const float* f3W, const float* f3b,
                                             float* __restrict__ ws) {
  int idx = blockIdx.x * 256 + threadIdx.x;
  const float TWO_PI = 6.2831853071795864769f;
  if (idx < 512) {
  } else if (idx < 992) {
    int e = idx - 512, d = e / 24, n = e % 24;
    float c = 0.f, s = 0.f;
    for (int k = 0; k < 24; ++k) {
      int j = (k * n) % 24;
      float ang = TWO_PI * (float)j / 24.f;
      float w = linW[d * 24 + k];
      c += w * cosf(ang);
      s -= w * sinf(ang);
    }
    ws[OFF_C + e] = c;
    ws[OFF_S + e] = s;
  } else if (idx < 3040) {
    int e = idx - 992, i = e >> 8, co = (e >> 4) & 15, ci = e & 15;
    size_t base = (size_t)(i * 16 + co) * 64 + ci;
    float W0 = gconvW[base];
    float W1 = gconvW[base + 16];
    float W2 = gconvW[base + 32];
    float W3 = gconvW[base + 48];
    size_t o = OFF_WEFF + (size_t)i * 768 + co * 16 + ci;
    ws[o]       = EPS_ * (W0 + W2) + EPS_ * EPS_ * (W1 + W3);
    ws[o + 256] = (W0 - W2) + 2.f * EPS_ * (W1 - W3);
    ws[o + 512] = W1 + W3;
  } else if (idx < 36320) {
    int e = idx - 3040;
    if (e < 32768) {
      int k = e >> 9, w = e & 511;
      float v = 0.f;
      if (k < 20) v = f1W[w * 20 + k];
      else if (k < 40) v = f2W[w * 20 + k - 20];
      else if (k < 60) v = f3W[w * 20 + k - 40];
      ws[OFF_WCT + e] = v;
    } else {
      int w = e - 32768;
      ws[OFF_WCT + e] = f1b[w] + f2b[w] + f3b[w];
    }
  } else if (idx < 36320 + 278528) {
    int e = idx - 36320;
    int m = e / 544, kk = e - m * 544;
    float val = 0.f;
    if (kk < 514) {
      int k = kk >> 1;
      int j = (k * m) & 511;
      float ang = TWO_PI * (float)j * (1.f / 512.f);
      val = ((kk & 1) ? sinf(ang) : cosf(ang)) * (1.f / 512.f);
    }
    ushort_t h = f2bf(val);
    float hf = tofu(h);
    ((ushort_t*)(ws + OFF_TBH))[e] = h;
    ((ushort_t*)(ws + OFF_TBL))[e] = f2bf(val - hf);
  }
}

// ---------- FFT(24) folded into lin_W ----------
__global__ __launch_bounds__(256) void k_fft(const float* __restrict__ in,
                                             const float* __restrict__ linb,
                                             const float* __restrict__ ws,
                                             float* __restrict__ Rw, float* __restrict__ Iw,
                                             float* __restrict__ G) {
  __shared__ float Cl[480], Sl[480], lb[20];
  int tid = threadIdx.x;
  for (int e = tid; e < 480; e += 256) { Cl[e] = ws[OFF_C + e]; Sl[e] = ws[OFF_S + e]; }
  if (tid < 20) lb[tid] = linb[tid];
  __syncthreads();
  int gid = blockIdx.x * 256 + tid;
  int b = gid >> 9, v = gid & 511;
  float xr[24];
#pragma unroll
  for (int t = 0; t < 12; ++t) {
    size_t ib = (((size_t)t * 32 + b) * 512 + v) * 2;
    xr[2 * t] = in[ib];
    xr[2 * t + 1] = in[ib + 1];
  }
  size_t gbv = (size_t)b * 512 + v;
  for (int d = 0; d < 20; ++d) {
    float R = lb[d], I = lb[d];
#pragma unroll
    for (int n = 0; n < 24; ++n) {
      R = fmaf(xr[n], Cl[d * 24 + n], R);
      I = fmaf(xr[n], Sl[d * 24 + n], I);
    }
    Rw[gbv * 20 + d] = R;
    Iw[gbv * 20 + d] = I;
    G[gbv * 64 + 20 + d] = sqrtf(R * R + I * I);
    G[gbv * 64 + 40 + d] = atanf(R / (I + 1e-4f));
  }
  G[gbv * 64 + 60] = 0.f; G[gbv * 64 + 61] = 0.f;
  G[gbv * 64 + 62] = 0.f; G[gbv * 64 + 63] = 0.f;
}

// ---------- pack irfft A-matrix ----------
__global__ __launch_bounds__(256) void k_irprep(const float* __restrict__ Rw,
                                                const float* __restrict__ Iw,
                                                ushort_t* __restrict__ Ahi,
                                                ushort_t* __restrict__ Alo) {
  int e = blockIdx.x * 256 + threadIdx.x;
  if (e >= 348160) return;
  int row = e / 544, kk = e - row * 544;
  int b = row / 20, d = row - b * 20;
  float val = 0.f;
  if (kk < 514) {
    int k = kk >> 1;
    float ck = (k == 0 || k == 256) ? 1.f : 2.f;
    size_t src = ((size_t)b * 512 + k) * 20 + d;
    val = (kk & 1) ? (-ck * Iw[src]) : (ck * Rw[src]);
  }
  ushort_t h = f2bf(val);
  Ahi[e] = h;
  Alo[e] = f2bf(val - tofu(h));
}

// ---------- irfft as MFMA GEMM ----------
__global__ __launch_bounds__(512) void k_irgemm(const ushort_t* __restrict__ Ah_g,
                                                const ushort_t* __restrict__ Al_g,
                                                const ushort_t* __restrict__ Bh_g,
                                                const ushort_t* __restrict__ Bl_g,
                                                float* __restrict__ G) {
  __shared__ ushort_t Ah[128 * 40], Al[128 * 40], Bh[64 * 40], Bl[64 * 40];
  int tid = threadIdx.x;
  int lane = tid & 63, wv = tid >> 6;
  int quad = lane >> 4, l15 = lane & 15;
  int wr = wv >> 1, wc = wv & 1;
  int m0 = blockIdx.x * 128;
  int nv0 = blockIdx.y * 64;
  int srow = tid >> 2, seg = tid & 3;
  size_t baseA = (size_t)(m0 + srow) * 544 + seg * 8;
  size_t baseB = (size_t)(nv0 + (srow & 63)) * 544 + seg * 8;
  int slo = srow * 40 + seg * 8;
  uint4 pAh = *(const uint4*)&Ah_g[baseA];
  uint4 pAl = *(const uint4*)&Al_g[baseA];
  uint4 pBh, pBl;
  if (tid < 256) { pBh = *(const uint4*)&Bh_g[baseB]; pBl = *(const uint4*)&Bl_g[baseB]; }
  f32x4 acc[2][2] = {};
  for (int kt = 0; kt < 17; ++kt) {
    *(uint4*)&Ah[slo] = pAh;
    *(uint4*)&Al[slo] = pAl;
    if (tid < 256) { *(uint4*)&Bh[slo] = pBh; *(uint4*)&Bl[slo] = pBl; }
    __syncthreads();
    if (kt < 16) {
      int ko = (kt + 1) * 32;
      pAh = *(const uint4*)&Ah_g[baseA + ko];
      pAl = *(const uint4*)&Al_g[baseA + ko];
      if (tid < 256) { pBh = *(const uint4*)&Bh_g[baseB + ko]; pBl = *(const uint4*)&Bl_g[baseB + ko]; }
    }
    bf16x8 afh[2], afl[2], bfh[2], bfl[2];
#pragma unroll
    for (int i = 0; i < 2; ++i) {
      int mr = (wr * 32 + i * 16 + l15) * 40 + quad * 8;
      afh[i] = *(const bf16x8*)&Ah[mr];
      afl[i] = *(const bf16x8*)&Al[mr];
    }
#pragma unroll
    for (int j = 0; j < 2; ++j) {
      int nr = (wc * 32 + j * 16 + l15) * 40 + quad * 8;
      bfh[j] = *(const bf16x8*)&Bh[nr];
      bfl[j] = *(const bf16x8*)&Bl[nr];
    }
#pragma unroll
    for (int i = 0; i < 2; ++i)
#pragma unroll
      for (int j = 0; j < 2; ++j) {
        acc[i][j] = __builtin_amdgcn_mfma_f32_16x16x32_bf16(afh[i], bfh[j], acc[i][j], 0, 0, 0);
        acc[i][j] = __builtin_amdgcn_mfma_f32_16x16x32_bf16(afh[i], bfl[j], acc[i][j], 0, 0, 0);
        acc[i][j] = __builtin_amdgcn_mfma_f32_16x16x32_bf16(afl[i], bfh[j], acc[i][j], 0, 0, 0);
      }
    __syncthreads();
  }
#pragma unroll
  for (int i = 0; i < 2; ++i)
#pragma unroll
    for (int j = 0; j < 2; ++j)
#pragma unroll
      for (int r = 0; r < 4; ++r) {
        int arow = m0 + wr * 32 + i * 16 + quad * 4 + r;
        int col = nv0 + wc * 32 + j * 16 + l15;
        int b = arow / 20, d = arow - b * 20;
        G[((size_t)b * 512 + col) * 64 + d] = acc[i][j][r];
      }
}

// ---------- adj partials: no atomics; grid (8,8,4), 8 batches/block ----------
__global__ __launch_bounds__(256) void k_adj(const float* __restrict__ G,
                                             const float* __restrict__ wct,
                                             float* __restrict__ padj) {
  __shared__ float As[64 * 68], Bs[64 * 68], bsl[64];
  int tid = threadIdx.x, tx = tid & 15, ty = tid >> 4;
  int w0 = blockIdx.x * 64, m0 = blockIdx.y * 64, z = blockIdx.z;
  for (int i = 0; i < 16; ++i) {
    int idx = tid + i * 256;
    Bs[(idx >> 6) * 68 + (idx & 63)] = wct[(size_t)(idx >> 6) * 512 + w0 + (idx & 63)];
  }
  if (tid < 64) bsl[tid] = wct[32768 + w0 + tid];
  float sum[4][4] = {};
  for (int bi = 0; bi < 8; ++bi) {
    int bb = z * 8 + bi;
    __syncthreads();
    for (int i = 0; i < 4; ++i) {
      int idx = tid + i * 256;
      int row = idx >> 4, seg = idx & 15;
      float4 g = *(const float4*)&G[((size_t)bb * 512 + m0 + row) * 64 + seg * 4];
      As[(seg * 4 + 0) * 68 + row] = g.x;
      As[(seg * 4 + 1) * 68 + row] = g.y;
      As[(seg * 4 + 2) * 68 + row] = g.z;
      As[(seg * 4 + 3) * 68 + row] = g.w;
    }
    __syncthreads();
    float dot[4][4] = {};
    for (int kk = 0; kk < 64; ++kk) {
      float4 a = *(const float4*)&As[kk * 68 + ty * 4];
      float4 b = *(const float4*)&Bs[kk * 68 + tx * 4];
      float ar[4] = {a.x, a.y, a.z, a.w}, br[4] = {b.x, b.y, b.z, b.w};
#pragma unroll
      for (int r = 0; r < 4; ++r)
#pragma unroll
        for (int c = 0; c < 4; ++c) dot[r][c] = fmaf(ar[r], br[c], dot[r][c]);
    }
#pragma unroll
    for (int r = 0; r < 4; ++r)
#pragma unroll
      for (int c = 0; c < 4; ++c)
        sum[r][c] += sigm((dot[r][c] + bsl[tx * 4 + c]) * (1.f / 3.f));
  }
  float* pz = padj + (size_t)z * 262144;
#pragma unroll
  for (int r = 0; r < 4; ++r)
#pragma unroll
    for (int c = 0; c < 4; ++c)
      pz[(size_t)(m0 + ty * 4 + r) * 512 + w0 + tx * 4 + c] = sum[r][c];
}

// ---------- finalize adj ----------
__global__ __launch_bounds__(256) void k_adjfin(const float* __restrict__ padj,
                                                float* __restrict__ adjw,
                                                void* __restrict__ outp,
                                                const float* __restrict__ flag) {
  int idx = blockIdx.x * 256 + threadIdx.x;
  float s = padj[idx] + padj[idx + 262144] + padj[idx + 524288] + padj[idx + 786432];
  float a = sigm(s * (1.f / 32.f));
  adjw[idx] = a;
  if (flag[0] > 0.5f) ((float*)outp)[196608 + idx] = a;
  else ((ushort_t*)outp)[196608 + idx] = f2bf(a);
}

// ---------- fp32 GEMM (adj2 = adj @ adj) ----------
__global__ __launch_bounds__(256) void k_gemm(const float* __restrict__ A,
                                              const float* __restrict__ B0,
                                              const float* __restrict__ B1,
                                              float* __restrict__ C, int ldc) {
  __shared__ float As[32][68];
  __shared__ float Bs[32][68];
  int bx = blockIdx.x, by = blockIdx.y;
  const float* __restrict__ Bp = (bx < 8) ? B0 : B1;
  int n0 = (bx & 7) * 64, m0 = by * 64;
  int tid = threadIdx.x, tx = tid & 15, ty = tid >> 4;
  float acc[4][4] = {};
  for (int kb = 0; kb < 512; kb += 32) {
#pragma unroll
    for (int s = 0; s < 2; ++s) {
      int f = tid + s * 256;
      int row = f >> 3, k4 = (f & 7) << 2;
      float4 a4 = *(const float4*)(A + (size_t)(m0 + row) * 512 + kb + k4);
      As[k4 + 0][row] = a4.x;
      As[k4 + 1][row] = a4.y;
      As[k4 + 2][row] = a4.z;
      As[k4 + 3][row] = a4.w;
      int kk = f >> 4, c4 = (f & 15) << 2;
      *(float4*)&Bs[kk][c4] = *(const float4*)(Bp + (size_t)(kb + kk) * 512 + n0 + c4);
    }
    __syncthreads();
#pragma unroll
    for (int kk = 0; kk < 32; ++kk) {
      float4 a = *(const float4*)&As[kk][ty << 2];
      float4 b = *(const float4*)&Bs[kk][tx << 2];
      float ar[4] = {a.x, a.y, a.z, a.w}, br[4] = {b.x, b.y, b.z, b.w};
#pragma unroll
      for (int r = 0; r < 4; ++r)
#pragma unroll
        for (int c = 0; c < 4; ++c) acc[r][c] = fmaf(ar[r], br[c], acc[r][c]);
    }
    __syncthreads();
  }
#pragma unroll
  for (int r = 0; r < 4; ++r) {
    float4 o = make_float4(acc[r][0], acc[r][1], acc[r][2], acc[r][3]);
    *(float4*)(C + (size_t)(m0 + (ty << 2) + r) * ldc + bx * 64 + (tx << 2)) = o;
  }
}

// ---------- split B = [adjT | adj2T] into bf16 hi/lo ----------
__global__ __launch_bounds__(256) void k_splitB(const float* __restrict__ adjw,
                                                const float* __restrict__ adj2w,
                                                ushort_t* __restrict__ Bh,
                                                ushort_t* __restrict__ Bl) {
  __shared__ float til[32][33];
  int tid = threadIdx.x;
  int k0 = blockIdx.x * 32;
  int nb = blockIdx.y;
  const float* src = (nb < 16) ? adjw : adj2w;
  int ns = (nb * 32) & 511;
  for (int i = 0; i < 4; ++i) {
    int idx = tid + i * 256;
    int r = idx >> 5, c = idx & 31;
    til[r][c] = src[(size_t)(k0 + r) * 512 + ns + c];
  }
  __syncthreads();
  for (int i = 0; i < 4; ++i) {
    int idx = tid + i * 256;
    int rr = idx >> 5, cc = idx & 31;
    float v = til[cc][rr];
    ushort_t h = f2bf(v);
    float hf = tofu(h);
    ushort_t l = f2bf(v - hf);
    size_t o = (size_t)(nb * 32 + rr) * 512 + k0 + cc;
    Bh[o] = h;
    Bl[o] = l;
  }
}

// ---------- start conv ----------
__global__ __launch_bounds__(256) void k_start(const float* __restrict__ in,
                                               const float* __restrict__ stW,
                                               const float* __restrict__ stb,
                                               float* __restrict__ X0) {
  __shared__ float w[32], bl[16];
  int tid = threadIdx.x;
  if (tid < 32) w[tid] = stW[tid];
  if (tid < 16) bl[tid] = stb[tid];
  __syncthreads();
  int blk = blockIdx.x;
  int b = blk / 26, rem = blk % 26, t = rem >> 1, v = (rem & 1) * 256 + tid;
  float f0 = 0.f, f1 = 0.f;
  if (t > 0) {
    size_t ib = (((size_t)(t - 1) * 32 + b) * 512 + v) * 2;
    f0 = in[ib];
    f1 = in[ib + 1];
  }
#pragma unroll
  for (int c = 0; c < 16; ++c)
    X0[((size_t)(b * 13 + t) * 16 + c) * 512 + v] = fmaf(w[c * 2], f0, fmaf(w[c * 2 + 1], f1, bl[c]));
}

// ---------- gated conv + skip + bf16 hi/lo split of U ----------
__global__ __launch_bounds__(256) void k_gate(const float* __restrict__ X,
                                              ushort_t* __restrict__ Uhi,
                                              ushort_t* __restrict__ Ulo,
                                              float* __restrict__ skip,
                                              const float* fW, const float* fb,
                                              const float* gW, const float* gb,
                                              const float* sW, const float* sb,
                                              int i, int L, int Lo, int d) {
  __shared__ float wf[512], wg[512], swl[256], fbl[16], gbl[16], sbl[16];
  int tid = threadIdx.x;
  for (int e = tid; e < 512; e += 256) { wf[e] = fW[i * 512 + e]; wg[e] = gW[i * 512 + e]; }
  if (tid < 256) swl[tid] = sW[i * 256 + tid];
  if (tid < 16) { fbl[tid] = fb[i * 16 + tid]; gbl[tid] = gb[i * 16 + tid]; sbl[tid] = sb[i * 16 + tid]; }
  __syncthreads();
  int blk = blockIdx.x;
  int b = blk / (2 * Lo), rem = blk % (2 * Lo), t = rem >> 1, v = (rem & 1) * 256 + tid;
  float x0[16], x1[16];
  size_t base0 = (size_t)(b * L + t) * 16 * 512 + v;
  size_t base1 = (size_t)(b * L + t + d) * 16 * 512 + v;
#pragma unroll
  for (int ci = 0; ci < 16; ++ci) { x0[ci] = X[base0 + ci * 512]; x1[ci] = X[base1 + ci * 512]; }
  float u[16];
#pragma unroll
  for (int co = 0; co < 16; ++co) {
    float f = fbl[co], g = gbl[co];
#pragma unroll
    for (int ci = 0; ci < 16; ++ci) {
      f = fmaf(wf[co * 32 + ci * 2], x0[ci], f);
      f = fmaf(wf[co * 32 + ci * 2 + 1], x1[ci], f);
      g = fmaf(wg[co * 32 + ci * 2], x0[ci], g);
      g = fmaf(wg[co * 32 + ci * 2 + 1], x1[ci], g);
    }
    float uu = tanh_fast(f) * sigm(g);
    u[co] = uu;
    ushort_t h = f2bf(uu);
    float hf = tofu(h);
    ushort_t l = f2bf(uu - hf);
    size_t o = ((size_t)(b * Lo + t) * 16 + co) * 512 + v;
    Uhi[o] = h;
    Ulo[o] = l;
  }
  if (t == Lo - 1) {
#pragma unroll
    for (int c = 0; c < 16; ++c) {
      float s = sbl[c];
#pragma unroll
      for (int ci = 0; ci < 16; ++ci) s = fmaf(swl[c * 16 + ci], u[ci], s);
      skip[((size_t)b * 16 + c) * 512 + v] += s;
    }
  }
}

// ---------- fused MFMA GEMM + combine + BN: LDS staging + prefetch, 256 thr, 128x32 tile ----------
// Grid (4*Lo, 16) = 768 blocks at Lo=12 -> 3 blocks/CU balanced; inter-block overlap hides
// barrier drain. ALL pipeline state in named scalars (R11 lesson: local arrays -> alloca ->
// ~100 MB/dispatch scratch write traffic; R11's only defect — math already validated).
__global__ __launch_bounds__(256) void k_mfmac(const ushort_t* __restrict__ Uhi,
                                               const ushort_t* __restrict__ Ulo,
                                               const ushort_t* __restrict__ Bh_g,
                                               const ushort_t* __restrict__ Bl_g,
                                               const float* __restrict__ Xres,
                                               float* __restrict__ Xn,
                                               const float* __restrict__ ws,
                                               const float* gcb, const float* bg,
                                               const float* bb2, const float* bm,
                                               const float* bv,
                                               int li, int L, int Lo, int d) {
  __shared__ __align__(16) char smem[33792];   // staging 30720 B, reused as yt 33792 B
  ushort_t* Ah = (ushort_t*)smem;              // [128][40]
  ushort_t* Al = Ah + 5120;
  ushort_t* Bh = Al + 5120;                    // [64][40]
  ushort_t* Bl = Bh + 2560;
  float* yt = (float*)smem;                    // [128][66]
  __shared__ float wx[256], wy1[256], wy2[256], gbl[16], bsc[16], bsh[16];
  int tid = threadIdx.x;
  const float* we = ws + OFF_WEFF + (size_t)li * 768;
  wx[tid] = we[tid]; wy1[tid] = we[256 + tid]; wy2[tid] = we[512 + tid];
  if (tid < 16) {
    gbl[tid] = gcb[li * 16 + tid];
    float sc = bg[li * 16 + tid] * rsqrtf(bv[li * 16 + tid] + 1e-5f);
    bsc[tid] = sc;
    bsh[tid] = bb2[li * 16 + tid] - bm[li * 16 + tid] * sc;
  }
  int lane = tid & 63, wr = tid >> 6;          // 4 waves; wr owns 32 A-rows
  int quad = lane >> 4, l15 = lane & 15;
  int m0 = blockIdx.x * 128;                   // A rows (fastest grid dim: XCD A-locality)
  int nv0 = blockIdx.y * 32;                   // v-range [nv0, nv0+32)
  // staging addresses — named scalars only
  int seg = tid & 3;
  int rowA0 = tid >> 2;                        // 0..63
  int rowA1 = rowA0 + 64;                      // 64..127
  int browl = rowA0;                           // 0..63: B rows (32 adjT + 32 adj2T)
  int brow = (browl < 32) ? (nv0 + browl) : (480 + nv0 + browl);
  size_t gA0 = (size_t)(m0 + rowA0) * 512 + seg * 8;
  size_t gA1 = (size_t)(m0 + rowA1) * 512 + seg * 8;
  size_t gB  = (size_t)brow * 512 + seg * 8;
  int lA0 = rowA0 * 40 + seg * 8;
  int lA1 = rowA1 * 40 + seg * 8;
  int lB  = browl * 40 + seg * 8;
  uint4 p0h = *(const uint4*)&Uhi[gA0];
  uint4 p0l = *(const uint4*)&Ulo[gA0];
  uint4 p1h = *(const uint4*)&Uhi[gA1];
  uint4 p1l = *(const uint4*)&Ulo[gA1];
  uint4 p2h = *(const uint4*)&Bh_g[gB];
  uint4 p2l = *(const uint4*)&Bl_g[gB];
  f32x4 acc[2][4] = {};
  for (int kt = 0; kt < 16; ++kt) {
    *(uint4*)&Ah[lA0] = p0h;
    *(uint4*)&Al[lA0] = p0l;
    *(uint4*)&Ah[lA1] = p1h;
    *(uint4*)&Al[lA1] = p1l;
    *(uint4*)&Bh[lB]  = p2h;
    *(uint4*)&Bl[lB]  = p2l;
    __syncthreads();
    if (kt < 15) {
      int ko = (kt + 1) * 32;
      p0h = *(const uint4*)&Uhi[gA0 + ko];
      p0l = *(const uint4*)&Ulo[gA0 + ko];
      p1h = *(const uint4*)&Uhi[gA1 + ko];
      p1l = *(const uint4*)&Ulo[gA1 + ko];
      p2h = *(const uint4*)&Bh_g[gB + ko];
      p2l = *(const uint4*)&Bl_g[gB + ko];
    }
    bf16x8 afh[2], afl[2], bfh[4], bfl[4];
#pragma unroll
    for (int i = 0; i < 2; ++i) {
      int mr = (wr * 32 + i * 16 + l15) * 40 + quad * 8;
      afh[i] = *(const bf16x8*)&Ah[mr];
      afl[i] = *(const bf16x8*)&Al[mr];
    }
#pragma unroll
    for (int j = 0; j < 4; ++j) {
      int nr = (j * 16 + l15) * 40 + quad * 8;
      bfh[j] = *(const bf16x8*)&Bh[nr];
      bfl[j] = *(const bf16x8*)&Bl[nr];
    }
#pragma unroll
    for (int i = 0; i < 2; ++i)
#pragma unroll
      for (int j = 0; j < 4; ++j) {
        acc[i][j] = __builtin_amdgcn_mfma_f32_16x16x32_bf16(afh[i], bfh[j], acc[i][j], 0, 0, 0);
        acc[i][j] = __builtin_amdgcn_mfma_f32_16x16x32_bf16(afh[i], bfl[j], acc[i][j], 0, 0, 0);
        acc[i][j] = __builtin_amdgcn_mfma_f32_16x16x32_bf16(afl[i], bfh[j], acc[i][j], 0, 0, 0);
      }
    __syncthreads();
  }
  // ---- fused epilogue (single pass: 8 groups x 32 v) ----
#pragma unroll
  for (int i = 0; i < 2; ++i)
#pragma unroll
    for (int j = 0; j < 4; ++j)
#pragma unroll
      for (int r = 0; r < 4; ++r) {
        int row = wr * 32 + i * 16 + quad * 4 + r;
        int col = (j & 1) * 16 + l15 + (j >> 1) * 32;   // 0..31 z1, 32..63 z2
        yt[row * 66 + col] = acc[i][j][r];
      }
  __syncthreads();
  int g = tid >> 5, lv = tid & 31;
  int gg = (m0 >> 4) + g;
  int b = gg / Lo, t = gg - b * Lo;
  size_t rb = (size_t)gg * 16;
  size_t resb = ((size_t)(b * L + t + d) * 16) * 512;
  int v = nv0 + lv;
  float uu[16], z1[16], z2[16];
#pragma unroll
  for (int ci = 0; ci < 16; ++ci) {
    size_t o = (rb + ci) * 512 + v;
    uu[ci] = tofu(Uhi[o]) + tofu(Ulo[o]);
    z1[ci] = yt[(g * 16 + ci) * 66 + lv];
    z2[ci] = yt[(g * 16 + ci) * 66 + 32 + lv];
  }
#pragma unroll
  for (int co = 0; co < 16; ++co) {
    float h = gbl[co];
#pragma unroll
    for (int ci = 0; ci < 16; ++ci) {
      h = fmaf(wx[co * 16 + ci], uu[ci], h);
      h = fmaf(wy1[co * 16 + ci], z1[ci], h);
      h = fmaf(wy2[co * 16 + ci], z2[ci], h);
    }
    float val = h + Xres[resb + co * 512 + v];
    val = fmaf(val, bsc[co], bsh[co]);
    Xn[(rb + co) * 512 + v] = val;
  }
}

// ---------- epilogue ----------
__global__ __launch_bounds__(256) void k_end(const float* __restrict__ skip,
                                             const float* e1W, const float* e1b,
                                             const float* e2W, const float* e2b,
                                             void* __restrict__ outp,
                                             const float* __restrict__ flag) {
  __shared__ float w1[256], b1[16], w2[192], b2[12];
  int tid = threadIdx.x;
  if (tid < 256) w1[tid] = e1W[tid];
  if (tid < 192) w2[tid] = e2W[tid];
  if (tid < 16) b1[tid] = e1b[tid];
  if (tid < 12) b2[tid] = e2b[tid];
  __syncthreads();
  float isf32 = flag[0];
  int gid = blockIdx.x * 256 + tid;
  int b = gid >> 9, v = gid & 511;
  float sk[16], e1[16];
#pragma unroll
  for (int ci = 0; ci < 16; ++ci) sk[ci] = fmaxf(skip[((size_t)b * 16 + ci) * 512 + v], 0.f);
#pragma unroll
  for (int c = 0; c < 16; ++c) {
    float a = b1[c];
#pragma unroll
    for (int ci = 0; ci < 16; ++ci) a = fmaf(w1[c * 16 + ci], sk[ci], a);
    e1[c] = fmaxf(a, 0.f);
  }
#pragma unroll
  for (int h = 0; h < 12; ++h) {
    float o = b2[h];
#pragma unroll
    for (int ci = 0; ci < 16; ++ci) o = fmaf(w2[h * 16 + ci], e1[ci], o);
    size_t oi = ((size_t)b * 12 + h) * 512 + v;
    if (isf32 > 0.5f) ((float*)outp)[oi] = o;
    else ((ushort_t*)outp)[oi] = f2bf(o);
  }
}

extern "C" void kernel_launch(void* const* d_in, const int* in_sizes, int n_in,
                              void* d_out, int out_size, void* d_ws, size_t ws_size,
                              hipStream_t stream) {
  float* ws = (float*)d_ws;
  if (ws_size < WS_TOTAL * sizeof(float)) return;

  static const int CSZ[27] = {393216, 32, 16, 4096, 128, 4096, 128, 2048, 128, 8192, 128,
                              128, 128, 128, 128, 256, 16, 192, 12, 480, 20,
                              10240, 512, 10240, 512, 10240, 512};
  float* cv[27];
  {
    size_t off = OFF_CIN;
    for (int i = 0; i < 27; ++i) { cv[i] = ws + off; off += (size_t)CSZ[i]; }
  }
  float* flag = ws + OFF_FLAG;

  k_detect<<<1, 256, 0, stream>>>(d_in[0], flag);
  P26 ps;
  for (int i = 0; i < 26; ++i) ps.p[i] = d_in[i + 1];
  k_convall<<<590, 256, 0, stream>>>(d_in[0], ps, cv[0], cv[1], flag);

  const float* IN = cv[0];
  const float* stW = cv[1];  const float* stb = cv[2];
  const float* fW = cv[3];   const float* fb = cv[4];
  const float* gW = cv[5];   const float* gb = cv[6];
  const float* sW = cv[7];   const float* sb = cv[8];
  const float* gcW = cv[9];  const float* gcb = cv[10];
  const float* bng = cv[11]; const float* bnb = cv[12];
  const float* bnm = cv[13]; const float* bnv = cv[14];
  const float* e1W = cv[15]; const float* e1b = cv[16];
  const float* e2W = cv[17]; const float* e2b = cv[18];
  const float* linW = cv[19]; const float* linb = cv[20];
  const float* f1W = cv[21]; const float* f1b = cv[22];
  const float* f2W = cv[23]; const float* f2b = cv[24];
  const float* f3W = cv[25]; const float* f3b = cv[26];

  hipMemsetAsync(ws + OFF_SKIP, 0, (size_t)B_ * 16 * V_ * sizeof(float), stream);
  k_pre<<<1230, 256, 0, stream>>>(linW, gcW, f1W, f1b, f2W, f2b, f3W, f3b, ws);
  k_fft<<<64, 256, 0, stream>>>(IN, linb, ws, ws + OFF_R, ws + OFF_I, ws + OFF_G);
  k_irprep<<<1360, 256, 0, stream>>>(ws + OFF_R, ws + OFF_I,
                                     (ushort_t*)(ws + OFF_TAH), (ushort_t*)(ws + OFF_TAL));
  k_irgemm<<<dim3(5, 8), 512, 0, stream>>>((ushort_t*)(ws + OFF_TAH), (ushort_t*)(ws + OFF_TAL),
                                           (ushort_t*)(ws + OFF_TBH), (ushort_t*)(ws + OFF_TBL),
                                           ws + OFF_G);
  k_adj<<<dim3(8, 8, 4), 256, 0, stream>>>(ws + OFF_G, ws + OFF_WCT, ws + OFF_PADJ);
  k_adjfin<<<1024, 256, 0, stream>>>(ws + OFF_PADJ, ws + OFF_ADJ, d_out, flag);
  k_gemm<<<dim3(8, 8), 256, 0, stream>>>(ws + OFF_ADJ, ws + OFF_ADJ, ws + OFF_ADJ,
                                         ws + OFF_ADJ2, 512);
  k_splitB<<<dim3(16, 32), 256, 0, stream>>>(ws + OFF_ADJ, ws + OFF_ADJ2,
                                             (ushort_t*)(ws + OFF_BTHI),
                                             (ushort_t*)(ws + OFF_BTLO));
  k_start<<<832, 256, 0, stream>>>(IN, stW, stb, ws + OFF_X0);

  float* cur = ws + OFF_X0;
  float* nxt = ws + OFF_X1;
  ushort_t* UHI = (ushort_t*)(ws + OFF_UHI);
  ushort_t* ULO = (ushort_t*)(ws + OFF_ULO);
  int L = 13;
  const int dils[8] = {1, 2, 1, 2, 1, 2, 1, 2};
  for (int i = 0; i < 8; ++i) {
    int d = dils[i], Lo = L - d;
    k_gate<<<64 * Lo, 256, 0, stream>>>(cur, UHI, ULO, ws + OFF_SKIP,
                                        fW, fb, gW, gb, sW, sb, i, L, Lo, d);
    k_mfmac<<<dim3(4 * Lo, 16), 256, 0, stream>>>(UHI, ULO,
                                                  (ushort_t*)(ws + OFF_BTHI),
                                                  (ushort_t*)(ws + OFF_BTLO),
                                                  cur, nxt, ws,
                                                  gcb, bng, bnb, bnm, bnv, i, L, Lo, d);
    float* tmp = cur; cur = nxt; nxt = tmp;
    L = Lo;
  }
  k_end<<<64, 256, 0, stream>>>(ws + OFF_SKIP, e1W, e1b, e2W, e2b, d_out, flag);
}

// Round 13
// 525.330 us; speedup vs baseline: 1.6369x; 1.0345x over previous
//
#include <hip/hip_runtime.h>
#include <hip/hip_bf16.h>

using bf16 = __hip_bfloat16;
typedef unsigned short ushort_t;
typedef float f32x4 __attribute__((ext_vector_type(4)));
typedef short bf16x8 __attribute__((ext_vector_type(8)));

__device__ __forceinline__ float tof(bf16 x) { return __bfloat162float(x); }
__device__ __forceinline__ float tofu(ushort_t u) { return __uint_as_float((unsigned)u << 16); }
__device__ __forceinline__ ushort_t f2bf(float x) {
  unsigned u = __float_as_uint(x);
  return (ushort_t)((u + 0x7FFF + ((u >> 16) & 1)) >> 16);  // RNE
}
__device__ __forceinline__ float sigm(float x) { return 1.f / (1.f + __expf(-x)); }
__device__ __forceinline__ float tanh_fast(float x) {
  float e2 = __expf(2.f * x);
  return 1.f - 2.f / (e2 + 1.f);
}

#define B_ 32
#define V_ 512
#define EPS_ 0.3f

// ---- workspace layout (float elements) ----
constexpr size_t OFF_C    = 1024;       // 480
constexpr size_t OFF_S    = 1504;       // 480
constexpr size_t OFF_WEFF = 1984;       // 6144 [8][3][16][16]
constexpr size_t OFF_R    = 8128;       // [32][512][20]  (dead after irprep)
constexpr size_t OFF_I    = 335808;     // [32][512][20]
constexpr size_t OFF_G    = 663488;     // [32][512][64] (dead after k_adj)
constexpr size_t OFF_BTHI = 663488;     // bf16 Bf_hi [64][16][64][8] frag-major (reuses G)
constexpr size_t OFF_BTLO = 925632;     // bf16 Bf_lo
constexpr size_t OFF_ADJ  = 1712064;    // [512][512]
constexpr size_t OFF_ADJ2 = 1974208;    // [512][512]
constexpr size_t OFF_SKIP = 2236352;    // [32][16][512]
constexpr size_t OFF_X0   = 2498496;    // [32][13][16][512]
constexpr size_t OFF_X1   = 5906368;    // layer ping-pong; pre-loop scratch below:
constexpr size_t OFF_TBH  = 5906368;    // bf16 Bt_hi [512][544]
constexpr size_t OFF_TBL  = 6045632;
constexpr size_t OFF_TAH  = 6184896;    // bf16 A_hi [640][544]
constexpr size_t OFF_TAL  = 6358976;
constexpr size_t OFF_UHI  = 9314240;    // bf16 Uf_hi [384][16][64][8] frag-major
constexpr size_t OFF_ULO  = 10887104;   // bf16 Uf_lo
constexpr size_t OFF_PADJ = 12722112;   // 4 x [512][512] partials
constexpr size_t OFF_WCT  = 13770688;   // WcT[64][512]+bsum[512] (must NOT alias R — R4/R5 bug)
constexpr size_t OFF_FLAG = 19013568;   // 8
constexpr size_t OFF_CIN  = 19013576;   // converted fp32 inputs (445952)
constexpr size_t WS_TOTAL = 19459584;

// ---------- dtype detection ----------
__global__ __launch_bounds__(256) void k_detect(const void* __restrict__ in0,
                                                float* __restrict__ flag) {
  __shared__ int cnt;
  if (threadIdx.x == 0) cnt = 0;
  __syncthreads();
  const unsigned short* u = (const unsigned short*)in0;
  int bad = 0;
  for (int i = threadIdx.x; i < 4096; i += 256) {
    int e = (u[i] >> 7) & 0xFF;
    if (e == 255 || (e != 0 && (e < 87 || e > 167))) bad++;
  }
  atomicAdd(&cnt, bad);
  __syncthreads();
  if (threadIdx.x == 0) flag[0] = (cnt > 200) ? 1.f : 0.f;
}

// ---------- all input conversion in one kernel ----------
struct P26 { const void* p[26]; };
__global__ __launch_bounds__(256) void k_convall(const void* __restrict__ in0, P26 ps,
                                                 float* __restrict__ dstin,
                                                 float* __restrict__ dstw,
                                                 const float* __restrict__ flag) {
  int tid = threadIdx.x;
  if (blockIdx.x < 384) {
    int i4 = blockIdx.x * 256 + tid;
    if (flag[0] > 0.5f) {
      ((float4*)dstin)[i4] = ((const float4*)in0)[i4];
    } else {
      ushort4 v = ((const ushort4*)in0)[i4];
      dstin[i4 * 4 + 0] = tofu(v.x);
      dstin[i4 * 4 + 1] = tofu(v.y);
      dstin[i4 * 4 + 2] = tofu(v.z);
      dstin[i4 * 4 + 3] = tofu(v.w);
    }
  } else {
    const int sz[26] = {32, 16, 4096, 128, 4096, 128, 2048, 128, 8192, 128,
                        128, 128, 128, 128, 256, 16, 192, 12, 480, 20,
                        10240, 512, 10240, 512, 10240, 512};
    int gid = (blockIdx.x - 384) * 256 + tid;
    if (gid >= 52736) return;
    int s = 0, off = 0;
    while (gid >= off + sz[s]) { off += sz[s]; ++s; }
    int local = gid - off;
    float v = (flag[0] > 0.5f) ? ((const float*)ps.p[s])[local]
                               : tofu(((const ushort_t*)ps.p[s])[local]);
    dstw[gid] = v;
  }
}

// ---------- precompute: folded-FFT mats, eff gconv weights, WcT+bsum, irfft B-mat ----------
__global__ __launch_bounds__(256) void k_pre(const float* __restrict__ linW,
                                             const float* __restrict__ gconvW,
                                             const float* f1W, const float* f1b,
                                             const float* f2W, const float* f2b,
                                             const float* f3W, const float* f3b,
                                             float* __restrict__ ws) {
  int idx = blockIdx.x * 256 + threadIdx.x;
  const float TWO_PI = 6.2831853071795864769f;
  if (idx < 512) {
  } else if (idx < 992) {
    int e = idx - 512, d = e / 24, n = e % 24;
    float c = 0.f, s = 0.f;
    for (int k = 0; k < 24; ++k) {
      int j = (k * n) % 24;
      float ang = TWO_PI * (float)j / 24.f;
      float w = linW[d * 24 + k];
      c += w * cosf(ang);
      s -= w * sinf(ang);
    }
    ws[OFF_C + e] = c;
    ws[OFF_S + e] = s;
  } else if (idx < 3040) {
    int e = idx - 992, i = e >> 8, co = (e >> 4) & 15, ci = e & 15;
    size_t base = (size_t)(i * 16 + co) * 64 + ci;
    float W0 = gconvW[base];
    float W1 = gconvW[base + 16];
    float W2 = gconvW[base + 32];
    float W3 = gconvW[base + 48];
    size_t o = OFF_WEFF + (size_t)i * 768 + co * 16 + ci;
    ws[o]       = EPS_ * (W0 + W2) + EPS_ * EPS_ * (W1 + W3);
    ws[o + 256] = (W0 - W2) + 2.f * EPS_ * (W1 - W3);
    ws[o + 512] = W1 + W3;
  } else if (idx < 36320) {
    int e = idx - 3040;
    if (e < 32768) {
      int k = e >> 9, w = e & 511;
      float v = 0.f;
      if (k < 20) v = f1W[w * 20 + k];
      else if (k < 40) v = f2W[w * 20 + k - 20];
      else if (k < 60) v = f3W[w * 20 + k - 40];
      ws[OFF_WCT + e] = v;
    } else {
      int w = e - 32768;
      ws[OFF_WCT + e] = f1b[w] + f2b[w] + f3b[w];
    }
  } else if (idx < 36320 + 278528) {
    int e = idx - 36320;
    int m = e / 544, kk = e - m * 544;
    float val = 0.f;
    if (kk < 514) {
      int k = kk >> 1;
      int j = (k * m) & 511;
      float ang = TWO_PI * (float)j * (1.f / 512.f);
      val = ((kk & 1) ? sinf(ang) : cosf(ang)) * (1.f / 512.f);
    }
    ushort_t h = f2bf(val);
    float hf = tofu(h);
    ((ushort_t*)(ws + OFF_TBH))[e] = h;
    ((ushort_t*)(ws + OFF_TBL))[e] = f2bf(val - hf);
  }
}

// ---------- FFT(24) folded into lin_W ----------
__global__ __launch_bounds__(256) void k_fft(const float* __restrict__ in,
                                             const float* __restrict__ linb,
                                             const float* __restrict__ ws,
                                             float* __restrict__ Rw, float* __restrict__ Iw,
                                             float* __restrict__ G) {
  __shared__ float Cl[480], Sl[480], lb[20];
  int tid = threadIdx.x;
  for (int e = tid; e < 480; e += 256) { Cl[e] = ws[OFF_C + e]; Sl[e] = ws[OFF_S + e]; }
  if (tid < 20) lb[tid] = linb[tid];
  __syncthreads();
  int gid = blockIdx.x * 256 + tid;
  int b = gid >> 9, v = gid & 511;
  float xr[24];
#pragma unroll
  for (int t = 0; t < 12; ++t) {
    size_t ib = (((size_t)t * 32 + b) * 512 + v) * 2;
    xr[2 * t] = in[ib];
    xr[2 * t + 1] = in[ib + 1];
  }
  size_t gbv = (size_t)b * 512 + v;
  for (int d = 0; d < 20; ++d) {
    float R = lb[d], I = lb[d];
#pragma unroll
    for (int n = 0; n < 24; ++n) {
      R = fmaf(xr[n], Cl[d * 24 + n], R);
      I = fmaf(xr[n], Sl[d * 24 + n], I);
    }
    Rw[gbv * 20 + d] = R;
    Iw[gbv * 20 + d] = I;
    G[gbv * 64 + 20 + d] = sqrtf(R * R + I * I);
    G[gbv * 64 + 40 + d] = atanf(R / (I + 1e-4f));
  }
  G[gbv * 64 + 60] = 0.f; G[gbv * 64 + 61] = 0.f;
  G[gbv * 64 + 62] = 0.f; G[gbv * 64 + 63] = 0.f;
}

// ---------- pack irfft A-matrix ----------
__global__ __launch_bounds__(256) void k_irprep(const float* __restrict__ Rw,
                                                const float* __restrict__ Iw,
                                                ushort_t* __restrict__ Ahi,
                                                ushort_t* __restrict__ Alo) {
  int e = blockIdx.x * 256 + threadIdx.x;
  if (e >= 348160) return;
  int row = e / 544, kk = e - row * 544;
  int b = row / 20, d = row - b * 20;
  float val = 0.f;
  if (kk < 514) {
    int k = kk >> 1;
    float ck = (k == 0 || k == 256) ? 1.f : 2.f;
    size_t src = ((size_t)b * 512 + k) * 20 + d;
    val = (kk & 1) ? (-ck * Iw[src]) : (ck * Rw[src]);
  }
  ushort_t h = f2bf(val);
  Ahi[e] = h;
  Alo[e] = f2bf(val - tofu(h));
}

// ---------- irfft as MFMA GEMM ----------
__global__ __launch_bounds__(512) void k_irgemm(const ushort_t* __restrict__ Ah_g,
                                                const ushort_t* __restrict__ Al_g,
                                                const ushort_t* __restrict__ Bh_g,
                                                const ushort_t* __restrict__ Bl_g,
                                                float* __restrict__ G) {
  __shared__ ushort_t Ah[128 * 40], Al[128 * 40], Bh[64 * 40], Bl[64 * 40];
  int tid = threadIdx.x;
  int lane = tid & 63, wv = tid >> 6;
  int quad = lane >> 4, l15 = lane & 15;
  int wr = wv >> 1, wc = wv & 1;
  int m0 = blockIdx.x * 128;
  int nv0 = blockIdx.y * 64;
  int srow = tid >> 2, seg = tid & 3;
  size_t baseA = (size_t)(m0 + srow) * 544 + seg * 8;
  size_t baseB = (size_t)(nv0 + (srow & 63)) * 544 + seg * 8;
  int slo = srow * 40 + seg * 8;
  uint4 pAh = *(const uint4*)&Ah_g[baseA];
  uint4 pAl = *(const uint4*)&Al_g[baseA];
  uint4 pBh, pBl;
  if (tid < 256) { pBh = *(const uint4*)&Bh_g[baseB]; pBl = *(const uint4*)&Bl_g[baseB]; }
  f32x4 acc[2][2] = {};
  for (int kt = 0; kt < 17; ++kt) {
    *(uint4*)&Ah[slo] = pAh;
    *(uint4*)&Al[slo] = pAl;
    if (tid < 256) { *(uint4*)&Bh[slo] = pBh; *(uint4*)&Bl[slo] = pBl; }
    __syncthreads();
    if (kt < 16) {
      int ko = (kt + 1) * 32;
      pAh = *(const uint4*)&Ah_g[baseA + ko];
      pAl = *(const uint4*)&Al_g[baseA + ko];
      if (tid < 256) { pBh = *(const uint4*)&Bh_g[baseB + ko]; pBl = *(const uint4*)&Bl_g[baseB + ko]; }
    }
    bf16x8 afh[2], afl[2], bfh[2], bfl[2];
#pragma unroll
    for (int i = 0; i < 2; ++i) {
      int mr = (wr * 32 + i * 16 + l15) * 40 + quad * 8;
      afh[i] = *(const bf16x8*)&Ah[mr];
      afl[i] = *(const bf16x8*)&Al[mr];
    }
#pragma unroll
    for (int j = 0; j < 2; ++j) {
      int nr = (wc * 32 + j * 16 + l15) * 40 + quad * 8;
      bfh[j] = *(const bf16x8*)&Bh[nr];
      bfl[j] = *(const bf16x8*)&Bl[nr];
    }
#pragma unroll
    for (int i = 0; i < 2; ++i)
#pragma unroll
      for (int j = 0; j < 2; ++j) {
        acc[i][j] = __builtin_amdgcn_mfma_f32_16x16x32_bf16(afh[i], bfh[j], acc[i][j], 0, 0, 0);
        acc[i][j] = __builtin_amdgcn_mfma_f32_16x16x32_bf16(afh[i], bfl[j], acc[i][j], 0, 0, 0);
        acc[i][j] = __builtin_amdgcn_mfma_f32_16x16x32_bf16(afl[i], bfh[j], acc[i][j], 0, 0, 0);
      }
    __syncthreads();
  }
#pragma unroll
  for (int i = 0; i < 2; ++i)
#pragma unroll
    for (int j = 0; j < 2; ++j)
#pragma unroll
      for (int r = 0; r < 4; ++r) {
        int arow = m0 + wr * 32 + i * 16 + quad * 4 + r;
        int col = nv0 + wc * 32 + j * 16 + l15;
        int b = arow / 20, d = arow - b * 20;
        G[((size_t)b * 512 + col) * 64 + d] = acc[i][j][r];
      }
}

// ---------- adj partials: no atomics; grid (8,8,4), 8 batches/block ----------
__global__ __launch_bounds__(256) void k_adj(const float* __restrict__ G,
                                             const float* __restrict__ wct,
                                             float* __restrict__ padj) {
  __shared__ float As[64 * 68], Bs[64 * 68], bsl[64];
  int tid = threadIdx.x, tx = tid & 15, ty = tid >> 4;
  int w0 = blockIdx.x * 64, m0 = blockIdx.y * 64, z = blockIdx.z;
  for (int i = 0; i < 16; ++i) {
    int idx = tid + i * 256;
    Bs[(idx >> 6) * 68 + (idx & 63)] = wct[(size_t)(idx >> 6) * 512 + w0 + (idx & 63)];
  }
  if (tid < 64) bsl[tid] = wct[32768 + w0 + tid];
  float sum[4][4] = {};
  for (int bi = 0; bi < 8; ++bi) {
    int bb = z * 8 + bi;
    __syncthreads();
    for (int i = 0; i < 4; ++i) {
      int idx = tid + i * 256;
      int row = idx >> 4, seg = idx & 15;
      float4 g = *(const float4*)&G[((size_t)bb * 512 + m0 + row) * 64 + seg * 4];
      As[(seg * 4 + 0) * 68 + row] = g.x;
      As[(seg * 4 + 1) * 68 + row] = g.y;
      As[(seg * 4 + 2) * 68 + row] = g.z;
      As[(seg * 4 + 3) * 68 + row] = g.w;
    }
    __syncthreads();
    float dot[4][4] = {};
    for (int kk = 0; kk < 64; ++kk) {
      float4 a = *(const float4*)&As[kk * 68 + ty * 4];
      float4 b = *(const float4*)&Bs[kk * 68 + tx * 4];
      float ar[4] = {a.x, a.y, a.z, a.w}, br[4] = {b.x, b.y, b.z, b.w};
#pragma unroll
      for (int r = 0; r < 4; ++r)
#pragma unroll
        for (int c = 0; c < 4; ++c) dot[r][c] = fmaf(ar[r], br[c], dot[r][c]);
    }
#pragma unroll
    for (int r = 0; r < 4; ++r)
#pragma unroll
      for (int c = 0; c < 4; ++c)
        sum[r][c] += sigm((dot[r][c] + bsl[tx * 4 + c]) * (1.f / 3.f));
  }
  float* pz = padj + (size_t)z * 262144;
#pragma unroll
  for (int r = 0; r < 4; ++r)
#pragma unroll
    for (int c = 0; c < 4; ++c)
      pz[(size_t)(m0 + ty * 4 + r) * 512 + w0 + tx * 4 + c] = sum[r][c];
}

// ---------- finalize adj ----------
__global__ __launch_bounds__(256) void k_adjfin(const float* __restrict__ padj,
                                                float* __restrict__ adjw,
                                                void* __restrict__ outp,
                                                const float* __restrict__ flag) {
  int idx = blockIdx.x * 256 + threadIdx.x;
  float s = padj[idx] + padj[idx + 262144] + padj[idx + 524288] + padj[idx + 786432];
  float a = sigm(s * (1.f / 32.f));
  adjw[idx] = a;
  if (flag[0] > 0.5f) ((float*)outp)[196608 + idx] = a;
  else ((ushort_t*)outp)[196608 + idx] = f2bf(a);
}

// ---------- fp32 GEMM (adj2 = adj @ adj) ----------
__global__ __launch_bounds__(256) void k_gemm(const float* __restrict__ A,
                                              const float* __restrict__ B0,
                                              const float* __restrict__ B1,
                                              float* __restrict__ C, int ldc) {
  __shared__ float As[32][68];
  __shared__ float Bs[32][68];
  int bx = blockIdx.x, by = blockIdx.y;
  const float* __restrict__ Bp = (bx < 8) ? B0 : B1;
  int n0 = (bx & 7) * 64, m0 = by * 64;
  int tid = threadIdx.x, tx = tid & 15, ty = tid >> 4;
  float acc[4][4] = {};
  for (int kb = 0; kb < 512; kb += 32) {
#pragma unroll
    for (int s = 0; s < 2; ++s) {
      int f = tid + s * 256;
      int row = f >> 3, k4 = (f & 7) << 2;
      float4 a4 = *(const float4*)(A + (size_t)(m0 + row) * 512 + kb + k4);
      As[k4 + 0][row] = a4.x;
      As[k4 + 1][row] = a4.y;
      As[k4 + 2][row] = a4.z;
      As[k4 + 3][row] = a4.w;
      int kk = f >> 4, c4 = (f & 15) << 2;
      *(float4*)&Bs[kk][c4] = *(const float4*)(Bp + (size_t)(kb + kk) * 512 + n0 + c4);
    }
    __syncthreads();
#pragma unroll
    for (int kk = 0; kk < 32; ++kk) {
      float4 a = *(const float4*)&As[kk][ty << 2];
      float4 b = *(const float4*)&Bs[kk][tx << 2];
      float ar[4] = {a.x, a.y, a.z, a.w}, br[4] = {b.x, b.y, b.z, b.w};
#pragma unroll
      for (int r = 0; r < 4; ++r)
#pragma unroll
        for (int c = 0; c < 4; ++c) acc[r][c] = fmaf(ar[r], br[c], acc[r][c]);
    }
    __syncthreads();
  }
#pragma unroll
  for (int r = 0; r < 4; ++r) {
    float4 o = make_float4(acc[r][0], acc[r][1], acc[r][2], acc[r][3]);
    *(float4*)(C + (size_t)(m0 + (ty << 2) + r) * ldc + bx * 64 + (tx << 2)) = o;
  }
}

// ---------- split B into bf16 hi/lo, MFMA-fragment-major layout ----------
// Bf[nblk=n>>4][kt=k>>5][lane=((k>>3)&3)*16+(n&15)][j=k&7]; n<512: adjT (y1), n>=512: adj2T (y2)
__global__ __launch_bounds__(256) void k_splitBf(const float* __restrict__ adjw,
                                                 const float* __restrict__ adj2w,
                                                 ushort_t* __restrict__ Bh,
                                                 ushort_t* __restrict__ Bl) {
  int e = blockIdx.x * 256 + threadIdx.x;   // 524288 = 1024 n x 512 k
  int n = e & 1023, k = e >> 10;
  float v = (n < 512) ? adjw[(size_t)k * 512 + n] : adj2w[(size_t)k * 512 + (n - 512)];
  ushort_t h = f2bf(v);
  float hf = tofu(h);
  ushort_t l = f2bf(v - hf);
  size_t o = (size_t)(n >> 4) * 8192 + (k >> 5) * 512 + ((k >> 3) & 3) * 128 + (n & 15) * 8 + (k & 7);
  Bh[o] = h;
  Bl[o] = l;
}

// ---------- start conv ----------
__global__ __launch_bounds__(256) void k_start(const float* __restrict__ in,
                                               const float* __restrict__ stW,
                                               const float* __restrict__ stb,
                                               float* __restrict__ X0) {
  __shared__ float w[32], bl[16];
  int tid = threadIdx.x;
  if (tid < 32) w[tid] = stW[tid];
  if (tid < 16) bl[tid] = stb[tid];
  __syncthreads();
  int blk = blockIdx.x;
  int b = blk / 26, rem = blk % 26, t = rem >> 1, v = (rem & 1) * 256 + tid;
  float f0 = 0.f, f1 = 0.f;
  if (t > 0) {
    size_t ib = (((size_t)(t - 1) * 32 + b) * 512 + v) * 2;
    f0 = in[ib];
    f1 = in[ib + 1];
  }
#pragma unroll
  for (int c = 0; c < 16; ++c)
    X0[((size_t)(b * 13 + t) * 16 + c) * 512 + v] = fmaf(w[c * 2], f0, fmaf(w[c * 2 + 1], f1, bl[c]));
}

// ---------- gated conv + skip + frag-major bf16 hi/lo U ----------
// Uf[group=b*Lo+t][kt=v>>5][lane=((v>>3)&3)*16+co][j=v&7]
__global__ __launch_bounds__(256) void k_gate(const float* __restrict__ X,
                                              ushort_t* __restrict__ Uhi,
                                              ushort_t* __restrict__ Ulo,
                                              float* __restrict__ skip,
                                              const float* fW, const float* fb,
                                              const float* gW, const float* gb,
                                              const float* sW, const float* sb,
                                              int i, int L, int Lo, int d) {
  __shared__ float wf[512], wg[512], swl[256], fbl[16], gbl[16], sbl[16];
  int tid = threadIdx.x;
  for (int e = tid; e < 512; e += 256) { wf[e] = fW[i * 512 + e]; wg[e] = gW[i * 512 + e]; }
  if (tid < 256) swl[tid] = sW[i * 256 + tid];
  if (tid < 16) { fbl[tid] = fb[i * 16 + tid]; gbl[tid] = gb[i * 16 + tid]; sbl[tid] = sb[i * 16 + tid]; }
  __syncthreads();
  int blk = blockIdx.x;
  int b = blk / (2 * Lo), rem = blk % (2 * Lo), t = rem >> 1, v = (rem & 1) * 256 + tid;
  float x0[16], x1[16];
  size_t base0 = (size_t)(b * L + t) * 16 * 512 + v;
  size_t base1 = (size_t)(b * L + t + d) * 16 * 512 + v;
#pragma unroll
  for (int ci = 0; ci < 16; ++ci) { x0[ci] = X[base0 + ci * 512]; x1[ci] = X[base1 + ci * 512]; }
  size_t ub = (size_t)(b * Lo + t) * 8192 + (v >> 5) * 512 + ((v >> 3) & 3) * 128 + (v & 7);
  float u[16];
#pragma unroll
  for (int co = 0; co < 16; ++co) {
    float f = fbl[co], g = gbl[co];
#pragma unroll
    for (int ci = 0; ci < 16; ++ci) {
      f = fmaf(wf[co * 32 + ci * 2], x0[ci], f);
      f = fmaf(wf[co * 32 + ci * 2 + 1], x1[ci], f);
      g = fmaf(wg[co * 32 + ci * 2], x0[ci], g);
      g = fmaf(wg[co * 32 + ci * 2 + 1], x1[ci], g);
    }
    float uu = tanh_fast(f) * sigm(g);
    u[co] = uu;
    ushort_t h = f2bf(uu);
    float hf = tofu(h);
    ushort_t l = f2bf(uu - hf);
    Uhi[ub + co * 8] = h;
    Ulo[ub + co * 8] = l;
  }
  if (t == Lo - 1) {
#pragma unroll
    for (int c = 0; c < 16; ++c) {
      float s = sbl[c];
#pragma unroll
      for (int ci = 0; ci < 16; ++ci) s = fmaf(swl[c * 16 + ci], u[ci], s);
      skip[((size_t)b * 16 + c) * 512 + v] += s;
    }
  }
}

// ---------- fused MFMA GEMM + combine + BN: frag-major direct-global, barrier-free K-loop ----------
// 256 thr, 4 waves, 128 rows x 32 v. Frag loads are base + lane*16B -> coalesced dwordx4,
// L2-served (B shared by consecutive same-XCD blocks; A by fixed-x blocks, same XCD).
// Named-scalar 2-deep pipeline (R11 lesson). LDS only for the 1-barrier yt epilogue.
__global__ __launch_bounds__(256) void k_mfmac(const ushort_t* __restrict__ Uf_hi,
                                               const ushort_t* __restrict__ Uf_lo,
                                               const ushort_t* __restrict__ Bf_hi,
                                               const ushort_t* __restrict__ Bf_lo,
                                               const float* __restrict__ Xres,
                                               float* __restrict__ Xn,
                                               const float* __restrict__ ws,
                                               const float* gcb, const float* bg,
                                               const float* bb2, const float* bm,
                                               const float* bv,
                                               int li, int L, int Lo, int d) {
  __shared__ float yt[128 * 66];               // 33.8 KB epilogue transpose
  __shared__ float wx[256], wy1[256], wy2[256], gbl[16], bsc[16], bsh[16];
  int tid = threadIdx.x;
  const float* we = ws + OFF_WEFF + (size_t)li * 768;
  wx[tid] = we[tid]; wy1[tid] = we[256 + tid]; wy2[tid] = we[512 + tid];
  if (tid < 16) {
    gbl[tid] = gcb[li * 16 + tid];
    float sc = bg[li * 16 + tid] * rsqrtf(bv[li * 16 + tid] + 1e-5f);
    bsc[tid] = sc;
    bsh[tid] = bb2[li * 16 + tid] - bm[li * 16 + tid] * sc;
  }
  int lane = tid & 63, wr = tid >> 6;
  int quad = lane >> 4, l15 = lane & 15;
  int m0 = blockIdx.x * 128;                   // A rows (fastest grid dim)
  int nv0 = blockIdx.y * 32;
  int g0 = m0 >> 4;
  int nb = nv0 >> 4;
  size_t a0 = (size_t)(g0 + wr * 2 + 0) * 8192 + lane * 8;
  size_t a1 = (size_t)(g0 + wr * 2 + 1) * 8192 + lane * 8;
  size_t b0 = (size_t)(nb + 0) * 8192 + lane * 8;
  size_t b1 = (size_t)(nb + 1) * 8192 + lane * 8;
  size_t b2 = (size_t)(nb + 32) * 8192 + lane * 8;
  size_t b3 = (size_t)(nb + 33) * 8192 + lane * 8;
  // current fragments (named scalars)
  bf16x8 cA0h = *(const bf16x8*)&Uf_hi[a0];
  bf16x8 cA0l = *(const bf16x8*)&Uf_lo[a0];
  bf16x8 cA1h = *(const bf16x8*)&Uf_hi[a1];
  bf16x8 cA1l = *(const bf16x8*)&Uf_lo[a1];
  bf16x8 cB0h = *(const bf16x8*)&Bf_hi[b0];
  bf16x8 cB0l = *(const bf16x8*)&Bf_lo[b0];
  bf16x8 cB1h = *(const bf16x8*)&Bf_hi[b1];
  bf16x8 cB1l = *(const bf16x8*)&Bf_lo[b1];
  bf16x8 cB2h = *(const bf16x8*)&Bf_hi[b2];
  bf16x8 cB2l = *(const bf16x8*)&Bf_lo[b2];
  bf16x8 cB3h = *(const bf16x8*)&Bf_hi[b3];
  bf16x8 cB3l = *(const bf16x8*)&Bf_lo[b3];
  f32x4 acc[2][4] = {};
  for (int kt = 0; kt < 16; ++kt) {
    int ko = ((kt + 1) & 15) * 512;            // wraps at last iter (loads dead)
    bf16x8 nA0h = *(const bf16x8*)&Uf_hi[a0 + ko];
    bf16x8 nA0l = *(const bf16x8*)&Uf_lo[a0 + ko];
    bf16x8 nA1h = *(const bf16x8*)&Uf_hi[a1 + ko];
    bf16x8 nA1l = *(const bf16x8*)&Uf_lo[a1 + ko];
    bf16x8 nB0h = *(const bf16x8*)&Bf_hi[b0 + ko];
    bf16x8 nB0l = *(const bf16x8*)&Bf_lo[b0 + ko];
    bf16x8 nB1h = *(const bf16x8*)&Bf_hi[b1 + ko];
    bf16x8 nB1l = *(const bf16x8*)&Bf_lo[b1 + ko];
    bf16x8 nB2h = *(const bf16x8*)&Bf_hi[b2 + ko];
    bf16x8 nB2l = *(const bf16x8*)&Bf_lo[b2 + ko];
    bf16x8 nB3h = *(const bf16x8*)&Bf_hi[b3 + ko];
    bf16x8 nB3l = *(const bf16x8*)&Bf_lo[b3 + ko];
    // i=0
    acc[0][0] = __builtin_amdgcn_mfma_f32_16x16x32_bf16(cA0h, cB0h, acc[0][0], 0, 0, 0);
    acc[0][0] = __builtin_amdgcn_mfma_f32_16x16x32_bf16(cA0h, cB0l, acc[0][0], 0, 0, 0);
    acc[0][0] = __builtin_amdgcn_mfma_f32_16x16x32_bf16(cA0l, cB0h, acc[0][0], 0, 0, 0);
    acc[0][1] = __builtin_amdgcn_mfma_f32_16x16x32_bf16(cA0h, cB1h, acc[0][1], 0, 0, 0);
    acc[0][1] = __builtin_amdgcn_mfma_f32_16x16x32_bf16(cA0h, cB1l, acc[0][1], 0, 0, 0);
    acc[0][1] = __builtin_amdgcn_mfma_f32_16x16x32_bf16(cA0l, cB1h, acc[0][1], 0, 0, 0);
    acc[0][2] = __builtin_amdgcn_mfma_f32_16x16x32_bf16(cA0h, cB2h, acc[0][2], 0, 0, 0);
    acc[0][2] = __builtin_amdgcn_mfma_f32_16x16x32_bf16(cA0h, cB2l, acc[0][2], 0, 0, 0);
    acc[0][2] = __builtin_amdgcn_mfma_f32_16x16x32_bf16(cA0l, cB2h, acc[0][2], 0, 0, 0);
    acc[0][3] = __builtin_amdgcn_mfma_f32_16x16x32_bf16(cA0h, cB3h, acc[0][3], 0, 0, 0);
    acc[0][3] = __builtin_amdgcn_mfma_f32_16x16x32_bf16(cA0h, cB3l, acc[0][3], 0, 0, 0);
    acc[0][3] = __builtin_amdgcn_mfma_f32_16x16x32_bf16(cA0l, cB3h, acc[0][3], 0, 0, 0);
    // i=1
    acc[1][0] = __builtin_amdgcn_mfma_f32_16x16x32_bf16(cA1h, cB0h, acc[1][0], 0, 0, 0);
    acc[1][0] = __builtin_amdgcn_mfma_f32_16x16x32_bf16(cA1h, cB0l, acc[1][0], 0, 0, 0);
    acc[1][0] = __builtin_amdgcn_mfma_f32_16x16x32_bf16(cA1l, cB0h, acc[1][0], 0, 0, 0);
    acc[1][1] = __builtin_amdgcn_mfma_f32_16x16x32_bf16(cA1h, cB1h, acc[1][1], 0, 0, 0);
    acc[1][1] = __builtin_amdgcn_mfma_f32_16x16x32_bf16(cA1h, cB1l, acc[1][1], 0, 0, 0);
    acc[1][1] = __builtin_amdgcn_mfma_f32_16x16x32_bf16(cA1l, cB1h, acc[1][1], 0, 0, 0);
    acc[1][2] = __builtin_amdgcn_mfma_f32_16x16x32_bf16(cA1h, cB2h, acc[1][2], 0, 0, 0);
    acc[1][2] = __builtin_amdgcn_mfma_f32_16x16x32_bf16(cA1h, cB2l, acc[1][2], 0, 0, 0);
    acc[1][2] = __builtin_amdgcn_mfma_f32_16x16x32_bf16(cA1l, cB2h, acc[1][2], 0, 0, 0);
    acc[1][3] = __builtin_amdgcn_mfma_f32_16x16x32_bf16(cA1h, cB3h, acc[1][3], 0, 0, 0);
    acc[1][3] = __builtin_amdgcn_mfma_f32_16x16x32_bf16(cA1h, cB3l, acc[1][3], 0, 0, 0);
    acc[1][3] = __builtin_amdgcn_mfma_f32_16x16x32_bf16(cA1l, cB3h, acc[1][3], 0, 0, 0);
    cA0h = nA0h; cA0l = nA0l; cA1h = nA1h; cA1l = nA1l;
    cB0h = nB0h; cB0l = nB0l; cB1h = nB1h; cB1l = nB1l;
    cB2h = nB2h; cB2l = nB2l; cB3h = nB3h; cB3l = nB3l;
  }
  // ---- fused epilogue (single pass: 8 groups x 32 v) ----
#pragma unroll
  for (int i = 0; i < 2; ++i)
#pragma unroll
    for (int j = 0; j < 4; ++j)
#pragma unroll
      for (int r = 0; r < 4; ++r) {
        int row = wr * 32 + i * 16 + quad * 4 + r;
        int col = (j & 1) * 16 + l15 + (j >> 1) * 32;   // 0..31 z1, 32..63 z2
        yt[row * 66 + col] = acc[i][j][r];
      }
  __syncthreads();
  int g = tid >> 5, lv = tid & 31;
  int gg = g0 + g;
  int b = gg / Lo, t = gg - b * Lo;
  size_t rb = (size_t)gg * 8192;
  size_t resb = ((size_t)(b * L + t + d) * 16) * 512;
  int v = nv0 + lv;
  size_t ub = rb + (v >> 5) * 512 + ((v >> 3) & 3) * 128 + (v & 7);
  float uu[16], z1[16], z2[16];
#pragma unroll
  for (int ci = 0; ci < 16; ++ci) {
    size_t o = ub + ci * 8;
    uu[ci] = tofu(Uf_hi[o]) + tofu(Uf_lo[o]);
    z1[ci] = yt[(g * 16 + ci) * 66 + lv];
    z2[ci] = yt[(g * 16 + ci) * 66 + 32 + lv];
  }
#pragma unroll
  for (int co = 0; co < 16; ++co) {
    float h = gbl[co];
#pragma unroll
    for (int ci = 0; ci < 16; ++ci) {
      h = fmaf(wx[co * 16 + ci], uu[ci], h);
      h = fmaf(wy1[co * 16 + ci], z1[ci], h);
      h = fmaf(wy2[co * 16 + ci], z2[ci], h);
    }
    float val = h + Xres[resb + co * 512 + v];
    val = fmaf(val, bsc[co], bsh[co]);
    Xn[((size_t)gg * 16 + co) * 512 + v] = val;
  }
}

// ---------- epilogue ----------
__global__ __launch_bounds__(256) void k_end(const float* __restrict__ skip,
                                             const float* e1W, const float* e1b,
                                             const float* e2W, const float* e2b,
                                             void* __restrict__ outp,
                                             const float* __restrict__ flag) {
  __shared__ float w1[256], b1[16], w2[192], b2[12];
  int tid = threadIdx.x;
  if (tid < 256) w1[tid] = e1W[tid];
  if (tid < 192) w2[tid] = e2W[tid];
  if (tid < 16) b1[tid] = e1b[tid];
  if (tid < 12) b2[tid] = e2b[tid];
  __syncthreads();
  float isf32 = flag[0];
  int gid = blockIdx.x * 256 + tid;
  int b = gid >> 9, v = gid & 511;
  float sk[16], e1[16];
#pragma unroll
  for (int ci = 0; ci < 16; ++ci) sk[ci] = fmaxf(skip[((size_t)b * 16 + ci) * 512 + v], 0.f);
#pragma unroll
  for (int c = 0; c < 16; ++c) {
    float a = b1[c];
#pragma unroll
    for (int ci = 0; ci < 16; ++ci) a = fmaf(w1[c * 16 + ci], sk[ci], a);
    e1[c] = fmaxf(a, 0.f);
  }
#pragma unroll
  for (int h = 0; h < 12; ++h) {
    float o = b2[h];
#pragma unroll
    for (int ci = 0; ci < 16; ++ci) o = fmaf(w2[h * 16 + ci], e1[ci], o);
    size_t oi = ((size_t)b * 12 + h) * 512 + v;
    if (isf32 > 0.5f) ((float*)outp)[oi] = o;
    else ((ushort_t*)outp)[oi] = f2bf(o);
  }
}

extern "C" void kernel_launch(void* const* d_in, const int* in_sizes, int n_in,
                              void* d_out, int out_size, void* d_ws, size_t ws_size,
                              hipStream_t stream) {
  float* ws = (float*)d_ws;
  if (ws_size < WS_TOTAL * sizeof(float)) return;

  static const int CSZ[27] = {393216, 32, 16, 4096, 128, 4096, 128, 2048, 128, 8192, 128,
                              128, 128, 128, 128, 256, 16, 192, 12, 480, 20,
                              10240, 512, 10240, 512, 10240, 512};
  float* cv[27];
  {
    size_t off = OFF_CIN;
    for (int i = 0; i < 27; ++i) { cv[i] = ws + off; off += (size_t)CSZ[i]; }
  }
  float* flag = ws + OFF_FLAG;

  k_detect<<<1, 256, 0, stream>>>(d_in[0], flag);
  P26 ps;
  for (int i = 0; i < 26; ++i) ps.p[i] = d_in[i + 1];
  k_convall<<<590, 256, 0, stream>>>(d_in[0], ps, cv[0], cv[1], flag);

  const float* IN = cv[0];
  const float* stW = cv[1];  const float* stb = cv[2];
  const float* fW = cv[3];   const float* fb = cv[4];
  const float* gW = cv[5];   const float* gb = cv[6];
  const float* sW = cv[7];   const float* sb = cv[8];
  const float* gcW = cv[9];  const float* gcb = cv[10];
  const float* bng = cv[11]; const float* bnb = cv[12];
  const float* bnm = cv[13]; const float* bnv = cv[14];
  const float* e1W = cv[15]; const float* e1b = cv[16];
  const float* e2W = cv[17]; const float* e2b = cv[18];
  const float* linW = cv[19]; const float* linb = cv[20];
  const float* f1W = cv[21]; const float* f1b = cv[22];
  const float* f2W = cv[23]; const float* f2b = cv[24];
  const float* f3W = cv[25]; const float* f3b = cv[26];

  hipMemsetAsync(ws + OFF_SKIP, 0, (size_t)B_ * 16 * V_ * sizeof(float), stream);
  k_pre<<<1230, 256, 0, stream>>>(linW, gcW, f1W, f1b, f2W, f2b, f3W, f3b, ws);
  k_fft<<<64, 256, 0, stream>>>(IN, linb, ws, ws + OFF_R, ws + OFF_I, ws + OFF_G);
  k_irprep<<<1360, 256, 0, stream>>>(ws + OFF_R, ws + OFF_I,
                                     (ushort_t*)(ws + OFF_TAH), (ushort_t*)(ws + OFF_TAL));
  k_irgemm<<<dim3(5, 8), 512, 0, stream>>>((ushort_t*)(ws + OFF_TAH), (ushort_t*)(ws + OFF_TAL),
                                           (ushort_t*)(ws + OFF_TBH), (ushort_t*)(ws + OFF_TBL),
                                           ws + OFF_G);
  k_adj<<<dim3(8, 8, 4), 256, 0, stream>>>(ws + OFF_G, ws + OFF_WCT, ws + OFF_PADJ);
  k_adjfin<<<1024, 256, 0, stream>>>(ws + OFF_PADJ, ws + OFF_ADJ, d_out, flag);
  k_gemm<<<dim3(8, 8), 256, 0, stream>>>(ws + OFF_ADJ, ws + OFF_ADJ, ws + OFF_ADJ,
                                         ws + OFF_ADJ2, 512);
  k_splitBf<<<2048, 256, 0, stream>>>(ws + OFF_ADJ, ws + OFF_ADJ2,
                                      (ushort_t*)(ws + OFF_BTHI),
                                      (ushort_t*)(ws + OFF_BTLO));
  k_start<<<832, 256, 0, stream>>>(IN, stW, stb, ws + OFF_X0);

  float* cur = ws + OFF_X0;
  float* nxt = ws + OFF_X1;
  ushort_t* UHI = (ushort_t*)(ws + OFF_UHI);
  ushort_t* ULO = (ushort_t*)(ws + OFF_ULO);
  int L = 13;
  const int dils[8] = {1, 2, 1, 2, 1, 2, 1, 2};
  for (int i = 0; i < 8; ++i) {
    int d = dils[i], Lo = L - d;
    k_gate<<<64 * Lo, 256, 0, stream>>>(cur, UHI, ULO, ws + OFF_SKIP,
                                        fW, fb, gW, gb, sW, sb, i, L, Lo, d);
    if (i < 7) {   // layer 7's combine output is dead (only skip feeds k_end)
      k_mfmac<<<dim3(4 * Lo, 16), 256, 0, stream>>>(UHI, ULO,
                                                    (ushort_t*)(ws + OFF_BTHI),
                                                    (ushort_t*)(ws + OFF_BTLO),
                                                    cur, nxt, ws,
                                                    gcb, bng, bnb, bnm, bnv, i, L, Lo, d);
    }
    float* tmp = cur; cur = nxt; nxt = tmp;
    L = Lo;
  }
  k_end<<<64, 256, 0, stream>>>(ws + OFF_SKIP, e1W, e1b, e2W, e2b, d_out, flag);
}